// Round 7
// baseline (756.982 us; speedup 1.0000x reference)
//
#include <hip/hip_runtime.h>
#include <hip/hip_bf16.h>

// Workspace layout (float indices). [COLSUM..DONE] zeroed by one memset each call.
#define OFF_COLSUM 0        // 64
#define OFF_S      64       // 4096
#define OFF_ACC    4160     // 8 loss accumulators (7 used)
#define OFF_DONE   4168     // 1 (int done-counter)
#define OFF_ZEND   4169     // memset extent (floats)
#define OFF_SHX    4176     // 64 BN shift xy
#define OFF_SHZ    4240     // 64 BN shift z
#define OFF_W1XS   4304     // ushort[4096] (w1_xy^T * sc, bf16, [ch j][k])
#define OFF_W1ZS   6352     // ushort[4096]
#define OFF_WSEGS  8400     // ushort[2048] (w_seg^T bf16, rows 20..31 = 0)

typedef __attribute__((ext_vector_type(8))) short bf16x8;
typedef __attribute__((ext_vector_type(4))) float f32x4;

__device__ __forceinline__ unsigned short f2bfh(float x) {
    __hip_bfloat16 h = __float2bfloat16(x);
    return *reinterpret_cast<unsigned short*>(&h);
}

union BF8 { bf16x8 v; unsigned short u[8]; };

__device__ __forceinline__ void gload_lds16(const void* g, void* l) {
    __builtin_amdgcn_global_load_lds((const __attribute__((address_space(1))) void*)g,
                                     (__attribute__((address_space(3))) void*)l, 16, 0, 0);
}

// fp32 staging layout (point-major, src-swizzled; proven R4):
//   16B unit i holds feat[r = i>>4][4*((i&15) ^ (r&15)) .. +3]

// ---------------- Pass 1: colsum + S = F^T F via MFMA ----------------
// NEW: bf16 channel-major convert pass between staging and frag-read.
// bf16 tile: 64 ch rows x 36 u32 words (32 pt-pairs + 4 pad). Word for
// (ch, pair p) at ch*36 + (p ^ (4*(ch>>3))): writes exactly 2 lanes/bank (free),
// b128 frag reads 4-word contiguous (reads are 4-aligned so XOR preserves runs).
__global__ __launch_bounds__(256, 3) void k_stats(const float* __restrict__ feat,
                                                  int N, int ntiles, int tpb,
                                                  float* __restrict__ ws) {
    __shared__ __align__(16) float f32t[2][4096];          // 32 KB
    __shared__ __align__(16) unsigned int bft[2][64 * 36]; // 18 KB
    const int t = threadIdx.x;
    const int lane = t & 63, l15 = lane & 15, grp = lane >> 4, wv = t >> 6;
    const int o = t & 7;           // ch-octet (channels 8o..8o+7)
    const int pp = t >> 3;         // pt-pair 0..31

    const f32x4 z4 = {0.f, 0.f, 0.f, 0.f};
    f32x4 acc[4] = {z4, z4, z4, z4};
    float cs[8] = {0.f, 0.f, 0.f, 0.f, 0.f, 0.f, 0.f, 0.f};

    // frag word offsets (tile-invariant): frag[s][h] = F[h*32+grp*8 ..][ch=g*16+l15]
    int roff[4][2];
#pragma unroll
    for (int s = 0; s < 4; s++) {
        const int g = (wv + s) & 3;
        const int ch = g * 16 + l15;
        const int ob = ch >> 3;
#pragma unroll
        for (int h = 0; h < 2; h++)
            roff[s][h] = ch * 36 + ((h * 16 + grp * 4) ^ (4 * ob));
    }
    // convert-pass fp32 read units (thread-invariant)
    const int r0 = 2 * pp, r1 = 2 * pp + 1;
    const int u00 = r0 * 16 + ((2 * o)     ^ (r0 & 15));
    const int u01 = r0 * 16 + ((2 * o + 1) ^ (r0 & 15));
    const int u10 = r1 * 16 + ((2 * o)     ^ (r1 & 15));
    const int u11 = r1 * 16 + ((2 * o + 1) ^ (r1 & 15));
    const int wbase = (8 * o) * 36 + (pp ^ (4 * o));

    const int ti0 = blockIdx.x * tpb;
    const int tiend = min(ti0 + tpb, ntiles);

    auto stage = [&](int bufi, int ti) {
        const int row0 = ti * 64;
        if (row0 + 64 <= N) {
#pragma unroll
            for (int c = 0; c < 4; c++) {
                const int r = (wv * 4 + c) * 4 + grp;
                const int u = l15 ^ (r & 15);
                gload_lds16(&feat[(size_t)(row0 + r) * 64 + u * 4],
                            &f32t[bufi][(wv * 4 + c) * 256]);
            }
        } else {
#pragma unroll
            for (int u2 = 0; u2 < 4; u2++) {
                const int i = t + u2 * 256;
                const int r = i >> 4, u = (i & 15) ^ (r & 15);
                float4 v = make_float4(0.f, 0.f, 0.f, 0.f);
                if (row0 + r < N) v = *(const float4*)&feat[(size_t)(row0 + r) * 64 + u * 4];
                *(float4*)&f32t[bufi][i * 4] = v;
            }
        }
    };

    auto convert = [&](int b) {
        const float4 a0 = *(const float4*)&f32t[b][u00 * 4];
        const float4 a1 = *(const float4*)&f32t[b][u01 * 4];
        const float4 c0 = *(const float4*)&f32t[b][u10 * 4];
        const float4 c1 = *(const float4*)&f32t[b][u11 * 4];
        const float lo[8] = {a0.x, a0.y, a0.z, a0.w, a1.x, a1.y, a1.z, a1.w}; // pt r0
        const float hi[8] = {c0.x, c0.y, c0.z, c0.w, c1.x, c1.y, c1.z, c1.w}; // pt r1
#pragma unroll
        for (int c = 0; c < 8; c++) {
            cs[c] += lo[c] + hi[c];
            bft[b][wbase + c * 36] =
                (unsigned)f2bfh(lo[c]) | ((unsigned)f2bfh(hi[c]) << 16);
        }
    };

    // depth-2 pipeline, one barrier per tile:
    // iter i: [barrier] stage(i+2) ; convert(i+1) ; MFMA(i)
    if (ti0 < tiend) stage(0, ti0);
    __syncthreads();
    if (ti0 < tiend) convert(0);
    if (ti0 + 1 < tiend) stage(1, ti0 + 1);

    for (int i = ti0; i < tiend; ++i) {
        const int ib = i & 1;
        __syncthreads();   // drains: stage(i+1) vmcnt, convert(i) lgkm, prev MFMA reads
        if (i + 2 < tiend) stage(ib, i + 2);
        if (i + 1 < tiend) convert(ib ^ 1);

        bf16x8 fr[4][2];
#pragma unroll
        for (int s = 0; s < 4; s++)
#pragma unroll
            for (int h = 0; h < 2; h++)
                fr[s][h] = *(const bf16x8*)&bft[ib][roff[s][h]];
#pragma unroll
        for (int s = 0; s < 4; s++) {
            acc[s] = __builtin_amdgcn_mfma_f32_16x16x32_bf16(fr[0][0], fr[s][0], acc[s], 0, 0, 0);
            acc[s] = __builtin_amdgcn_mfma_f32_16x16x32_bf16(fr[0][1], fr[s][1], acc[s], 0, 0, 0);
        }
    }

    // S[row = wv*16 + grp*4 + r][col = ((wv+s)&3)*16 + l15]
    float* S = ws + OFF_S;
#pragma unroll
    for (int s = 0; s < 4; s++) {
        const int gj = (wv + s) & 3;
#pragma unroll
        for (int r = 0; r < 4; r++)
            atomicAdd(&S[(wv * 16 + grp * 4 + r) * 64 + gj * 16 + l15], acc[s][r]);
    }
    // colsum: reduce cs[c] over lanes sharing o (xor 8/16/32), lanes 0..7 commit
#pragma unroll
    for (int c = 0; c < 8; c++) {
        float v = cs[c];
        v += __shfl_xor(v, 8); v += __shfl_xor(v, 16); v += __shfl_xor(v, 32);
        if ((lane >> 3) == 0) atomicAdd(&ws[OFF_COLSUM + 8 * o + c], v);
    }
}

// ------------- Prep: BN scale/shift; scaled bf16 weights (R4-proven) -------------
__global__ __launch_bounds__(256) void k_prep(
    const float* __restrict__ w1xy, const float* __restrict__ b1xy,
    const float* __restrict__ gxy,  const float* __restrict__ bexy,
    const float* __restrict__ w1z,  const float* __restrict__ b1z,
    const float* __restrict__ gz,   const float* __restrict__ bez,
    const float* __restrict__ wseg, float Nf, float* __restrict__ ws) {
    __shared__ float S[64][64];
    __shared__ float cs[64];
    const int t = threadIdx.x;

    for (int i = t; i < 4096; i += 256) ((float*)S)[i] = ws[OFF_S + i];
    if (t < 64) cs[t] = ws[OFF_COLSUM + t];
    __syncthreads();

    if (t < 128) {
        const int head = t >> 6, j = t & 63;
        const float* w1 = head ? w1z : w1xy;
        float w[64];
#pragma unroll
        for (int k = 0; k < 64; k++) w[k] = w1[k * 64 + j];
        float d = 0.f;
#pragma unroll
        for (int k = 0; k < 64; k++) d = fmaf(cs[k], w[k], d);
        float quad = 0.f;
#pragma unroll
        for (int k = 0; k < 64; k++) {
            float rd = 0.f;
#pragma unroll
            for (int l = 0; l < 64; l++) rd = fmaf(S[k][l], w[l], rd);
            quad = fmaf(w[k], rd, quad);
        }
        const float b1 = head ? b1z[j] : b1xy[j];
        const float mu  = d / Nf + b1;
        const float eh2 = quad / Nf + 2.f * b1 * d / Nf + b1 * b1;
        const float var = eh2 - mu * mu;
        const float g  = head ? gz[j]  : gxy[j];
        const float be = head ? bez[j] : bexy[j];
        const float sc = g * rsqrtf(var + 1e-3f);
        const float sh = be - mu * sc;
        ws[(head ? OFF_SHZ : OFF_SHX) + j] = sh;
        unsigned short* dst = (unsigned short*)(ws + (head ? OFF_W1ZS : OFF_W1XS));
#pragma unroll
        for (int k = 0; k < 64; k++) dst[j * 64 + k] = f2bfh(w[k] * sc);
    } else if (t < 160) {
        const int j = t - 128;  // 0..31
        unsigned short* dst = (unsigned short*)(ws + OFF_WSEGS);
        for (int k = 0; k < 64; k++)
            dst[j * 64 + k] = (j < 20) ? f2bfh(wseg[k * 20 + j]) : (unsigned short)0;
    }
}

// ---------------- Pass 2: swapped-operand MFMA heads + lane-local tail + finalize ----------------
__global__ __launch_bounds__(256, 2) void k_loss(
    const float* __restrict__ feat, const float* __restrict__ coord,
    const int* __restrict__ seg, const int* __restrict__ inst,
    const float* __restrict__ cent,
    const unsigned short* __restrict__ w1xs, const unsigned short* __restrict__ w1zs,
    const unsigned short* __restrict__ wsegs,
    const float* __restrict__ shxv, const float* __restrict__ shzv,
    const float* __restrict__ w2xy, const float* __restrict__ b2xy,
    const float* __restrict__ w2z,  const float* __restrict__ b2z,
    const float* __restrict__ bseg,
    int N, int ntiles, int tpb, float* __restrict__ acc, float* __restrict__ out) {
    __shared__ __align__(16) float ftile[2][4096];
    __shared__ float red[4][8];

    const int t = threadIdx.x;
    const int lane = t & 63, l15 = lane & 15, grp = lane >> 4, wv = t >> 6;

    // loop-invariant weight A-frags in VGPRs
    bf16x8 ax[4][2], az[4][2], ag[2][2];
#pragma unroll
    for (int nt = 0; nt < 4; nt++)
#pragma unroll
        for (int h = 0; h < 2; h++) {
            ax[nt][h] = *(const bf16x8*)&w1xs[(nt * 16 + l15) * 64 + grp * 8 + h * 32];
            az[nt][h] = *(const bf16x8*)&w1zs[(nt * 16 + l15) * 64 + grp * 8 + h * 32];
        }
#pragma unroll
    for (int nt = 0; nt < 2; nt++)
#pragma unroll
        for (int h = 0; h < 2; h++)
            ag[nt][h] = *(const bf16x8*)&wsegs[(nt * 16 + l15) * 64 + grp * 8 + h * 32];

    // per-lane constants: channel c = nt*16 + grp*4 + r
    float shx_c[4][4], shz_c[4][4], w20[4][4], w21[4][4], w2zc[4][4], bs_c[2][4];
#pragma unroll
    for (int nt = 0; nt < 4; nt++)
#pragma unroll
        for (int r = 0; r < 4; r++) {
            const int c = nt * 16 + grp * 4 + r;
            shx_c[nt][r] = shxv[c]; shz_c[nt][r] = shzv[c];
            w20[nt][r] = w2xy[c * 2]; w21[nt][r] = w2xy[c * 2 + 1];
            w2zc[nt][r] = w2z[c];
        }
#pragma unroll
    for (int nt = 0; nt < 2; nt++)
#pragma unroll
        for (int r = 0; r < 4; r++) {
            const int c = nt * 16 + grp * 4 + r;
            bs_c[nt][r] = (c < 20) ? bseg[c] : -1e30f;
        }
    const float pb0 = b2xy[0], pb1 = b2xy[1], pbz = b2z[0];

    float s_nll = 0.f, s_vf = 0.f, s_l1xy = 0.f, s_cosxy = 0.f;
    float s_l1z = 0.f, s_cosz = 0.f, s_mask = 0.f;

    const int ti0 = blockIdx.x * tpb;
    const int tiend = min(ti0 + tpb, ntiles);

    auto stage = [&](int bufi, int ti) {
        const int row0 = ti * 64;
        if (row0 + 64 <= N) {
#pragma unroll
            for (int c = 0; c < 4; c++) {
                const int r = (wv * 4 + c) * 4 + grp;
                const int u = l15 ^ (r & 15);
                gload_lds16(&feat[(size_t)(row0 + r) * 64 + u * 4],
                            &ftile[bufi][(wv * 4 + c) * 256]);
            }
        } else {
#pragma unroll
            for (int u2 = 0; u2 < 4; u2++) {
                const int i = t + u2 * 256;
                const int r = i >> 4, u = (i & 15) ^ (r & 15);
                float4 v = make_float4(0.f, 0.f, 0.f, 0.f);
                if (row0 + r < N) v = *(const float4*)&feat[(size_t)(row0 + r) * 64 + u * 4];
                *(float4*)&ftile[bufi][i * 4] = v;
            }
        }
    };

    // point-scalar prefetch one tile ahead
    int p_tg = -1, p_iv = -1;
    float p_c0 = 0.f, p_c1 = 0.f, p_c2 = 0.f, p_e0 = 0.f, p_e1 = 0.f, p_e2 = 0.f;
    auto ptload = [&](int ti) {
        const int gp = ti * 64 + wv * 16 + l15;
        const bool inb = (gp < N);
        p_tg = inb ? seg[gp] : -1;
        p_iv = inb ? inst[gp] : -1;
        if (inb) {
            p_c0 = coord[(size_t)gp * 3]; p_c1 = coord[(size_t)gp * 3 + 1]; p_c2 = coord[(size_t)gp * 3 + 2];
            p_e0 = cent[(size_t)gp * 3];  p_e1 = cent[(size_t)gp * 3 + 1];  p_e2 = cent[(size_t)gp * 3 + 2];
        } else {
            p_c0 = p_c1 = p_c2 = p_e0 = p_e1 = p_e2 = 0.f;
        }
    };

    if (ti0 < tiend) { stage(0, ti0); ptload(ti0); }
    int cur = 0;
    for (int ti = ti0; ti < tiend; ++ti) {
        const int tg = p_tg, iv = p_iv;
        const float c0 = p_c0, c1 = p_c1, c2 = p_c2, e0 = p_e0, e1 = p_e1, e2 = p_e2;

        __syncthreads();
        if (ti + 1 < tiend) { stage(cur ^ 1, ti + 1); ptload(ti + 1); }

        const int p = wv * 16 + l15;
        const float* fb = ftile[cur];
        const float4 q0 = *(const float4*)&fb[(p * 16 + ((grp * 2)     ^ l15)) * 4];
        const float4 q1 = *(const float4*)&fb[(p * 16 + ((grp * 2 + 1) ^ l15)) * 4];
        const float4 q2 = *(const float4*)&fb[(p * 16 + ((8 + grp * 2) ^ l15)) * 4];
        const float4 q3 = *(const float4*)&fb[(p * 16 + ((9 + grp * 2) ^ l15)) * 4];
        BF8 b0, b1;
        b0.u[0] = f2bfh(q0.x); b0.u[1] = f2bfh(q0.y); b0.u[2] = f2bfh(q0.z); b0.u[3] = f2bfh(q0.w);
        b0.u[4] = f2bfh(q1.x); b0.u[5] = f2bfh(q1.y); b0.u[6] = f2bfh(q1.z); b0.u[7] = f2bfh(q1.w);
        b1.u[0] = f2bfh(q2.x); b1.u[1] = f2bfh(q2.y); b1.u[2] = f2bfh(q2.z); b1.u[3] = f2bfh(q2.w);
        b1.u[4] = f2bfh(q3.x); b1.u[5] = f2bfh(q3.y); b1.u[6] = f2bfh(q3.z); b1.u[7] = f2bfh(q3.w);

        // ---- seg head + CE ----
        f32x4 cg0 = {bs_c[0][0], bs_c[0][1], bs_c[0][2], bs_c[0][3]};
        cg0 = __builtin_amdgcn_mfma_f32_16x16x32_bf16(ag[0][0], b0.v, cg0, 0, 0, 0);
        cg0 = __builtin_amdgcn_mfma_f32_16x16x32_bf16(ag[0][1], b1.v, cg0, 0, 0, 0);
        f32x4 cg1 = {bs_c[1][0], bs_c[1][1], bs_c[1][2], bs_c[1][3]};
        cg1 = __builtin_amdgcn_mfma_f32_16x16x32_bf16(ag[1][0], b0.v, cg1, 0, 0, 0);
        cg1 = __builtin_amdgcn_mfma_f32_16x16x32_bf16(ag[1][1], b1.v, cg1, 0, 0, 0);
        float lmax = cg0[0];
#pragma unroll
        for (int r = 1; r < 4; r++) lmax = fmaxf(lmax, cg0[r]);
#pragma unroll
        for (int r = 0; r < 4; r++) lmax = fmaxf(lmax, cg1[r]);
        lmax = fmaxf(lmax, __shfl_xor(lmax, 16));
        lmax = fmaxf(lmax, __shfl_xor(lmax, 32));
        float se = 0.f;
#pragma unroll
        for (int r = 0; r < 4; r++) se += __expf(cg0[r] - lmax);
#pragma unroll
        for (int r = 0; r < 4; r++) se += __expf(cg1[r] - lmax);
        se += __shfl_xor(se, 16); se += __shfl_xor(se, 32);
        const float lse = lmax + __logf(se);
        float lt = 0.f;
#pragma unroll
        for (int r = 0; r < 4; r++) lt += (grp * 4 + r == tg) ? cg0[r] : 0.f;
#pragma unroll
        for (int r = 0; r < 4; r++) lt += (16 + grp * 4 + r == tg) ? cg1[r] : 0.f;
        lt += __shfl_xor(lt, 16); lt += __shfl_xor(lt, 32);
        const float vf = (tg >= 0) ? 1.f : 0.f;
        s_nll += (lse - lt) * vf;
        s_vf += vf;

        // ---- xy + z heads (scale folded into weights, shift via C-init) ----
        float s0 = 0.f, s1 = 0.f, szv = 0.f;
#pragma unroll
        for (int nt = 0; nt < 4; nt++) {
            f32x4 cc = {shx_c[nt][0], shx_c[nt][1], shx_c[nt][2], shx_c[nt][3]};
            cc = __builtin_amdgcn_mfma_f32_16x16x32_bf16(ax[nt][0], b0.v, cc, 0, 0, 0);
            cc = __builtin_amdgcn_mfma_f32_16x16x32_bf16(ax[nt][1], b1.v, cc, 0, 0, 0);
#pragma unroll
            for (int r = 0; r < 4; r++) {
                const float hx = fmaxf(cc[r], 0.f);
                s0 = fmaf(hx, w20[nt][r], s0);
                s1 = fmaf(hx, w21[nt][r], s1);
            }
            f32x4 cz = {shz_c[nt][0], shz_c[nt][1], shz_c[nt][2], shz_c[nt][3]};
            cz = __builtin_amdgcn_mfma_f32_16x16x32_bf16(az[nt][0], b0.v, cz, 0, 0, 0);
            cz = __builtin_amdgcn_mfma_f32_16x16x32_bf16(az[nt][1], b1.v, cz, 0, 0, 0);
#pragma unroll
            for (int r = 0; r < 4; r++) {
                const float hz = fmaxf(cz[r], 0.f);
                szv = fmaf(hz, w2zc[nt][r], szv);
            }
        }
        s0 += __shfl_xor(s0, 16);  s0 += __shfl_xor(s0, 32);
        s1 += __shfl_xor(s1, 16);  s1 += __shfl_xor(s1, 32);
        szv += __shfl_xor(szv, 16); szv += __shfl_xor(szv, 32);
        const float p0 = s0 + pb0, p1 = s1 + pb1, pz = szv + pbz;

        const float mk = (iv >= 0) ? 1.f : 0.f;
        const float a0 = e0 - c0, a1 = e1 - c1, a2 = e2 - c2;
        s_l1xy += (fabsf(a0 - p0) + fabsf(a1 - p1)) * mk;
        const float na = sqrtf(a0 * a0 + a1 * a1) + 1e-8f;
        const float nb = sqrtf(p0 * p0 + p1 * p1) + 1e-8f;
        s_cosxy -= ((a0 * p0 + a1 * p1) / (na * nb)) * mk;
        s_l1z += fabsf(a2 - pz) * mk;
        const float naz = fabsf(a2) + 1e-8f, nbz = fabsf(pz) + 1e-8f;
        s_cosz -= ((a2 * pz) / (naz * nbz)) * mk;
        s_mask += mk;

        cur ^= 1;
    }

    // block reduction; values replicated x4 across grp -> scale 0.25
    float v[7] = {s_nll * 0.25f, s_vf * 0.25f, s_l1xy * 0.25f, s_cosxy * 0.25f,
                  s_l1z * 0.25f, s_cosz * 0.25f, s_mask * 0.25f};
#pragma unroll
    for (int i = 0; i < 7; i++) {
#pragma unroll
        for (int o = 32; o > 0; o >>= 1) v[i] += __shfl_down(v[i], o);
    }
    if (lane == 0) {
#pragma unroll
        for (int i = 0; i < 7; i++) red[wv][i] = v[i];
    }
    __syncthreads();
    if (t < 7) {
        float s = red[0][t] + red[1][t] + red[2][t] + red[3][t];
        atomicAdd(&acc[t], s);
    }
    __syncthreads();   // drains the acc atomics before the done handshake
    if (t == 0) {
        __threadfence();
        int* done = (int*)(acc + (OFF_DONE - OFF_ACC));
        if (atomicAdd(done, 1) == (int)gridDim.x - 1) {
            __threadfence();
            float sv[7];
#pragma unroll
            for (int i = 0; i < 7; i++) sv[i] = atomicAdd(&acc[i], 0.f);
            const float segl = sv[0] / sv[1];
            const float den = sv[6] + 1e-8f;
            const float l1xy = sv[2] / den, cosxy = sv[3] / den;
            const float l1z = sv[4] / den, cosz = sv[5] / den;
            out[0] = segl + l1xy + l1xy + 0.5f * (l1z + cosz);
            out[1] = segl;
            out[2] = l1xy;
            out[3] = cosxy;
            out[4] = l1z;
            out[5] = cosz;
        }
    }
}

extern "C" void kernel_launch(void* const* d_in, const int* in_sizes, int n_in,
                              void* d_out, int out_size, void* d_ws, size_t ws_size,
                              hipStream_t stream) {
    const float* feat  = (const float*)d_in[0];
    const float* coord = (const float*)d_in[1];
    const int*   segm  = (const int*)d_in[2];
    const int*   inst  = (const int*)d_in[3];
    const float* cent  = (const float*)d_in[4];
    const float* w1xy  = (const float*)d_in[5];
    const float* b1xy  = (const float*)d_in[6];
    const float* gxy   = (const float*)d_in[7];
    const float* bexy  = (const float*)d_in[8];
    const float* w2xy  = (const float*)d_in[9];
    const float* b2xy  = (const float*)d_in[10];
    const float* w1z   = (const float*)d_in[11];
    const float* b1z   = (const float*)d_in[12];
    const float* gz    = (const float*)d_in[13];
    const float* bez   = (const float*)d_in[14];
    const float* w2z   = (const float*)d_in[15];
    const float* b2z   = (const float*)d_in[16];
    const float* wseg  = (const float*)d_in[17];
    const float* bseg  = (const float*)d_in[18];

    const int N = in_sizes[0] / 64;
    float* ws = (float*)d_ws;
    const int ntiles = (N + 63) >> 6;

    const int grid_s = 768;
    const int tpb_s = (ntiles + grid_s - 1) / grid_s;
    const int grid_l = 512;
    const int tpb_l = (ntiles + grid_l - 1) / grid_l;

    hipMemsetAsync(d_ws, 0, OFF_ZEND * sizeof(float), stream);

    k_stats<<<grid_s, 256, 0, stream>>>(feat, N, ntiles, tpb_s, ws);
    k_prep<<<1, 256, 0, stream>>>(w1xy, b1xy, gxy, bexy, w1z, b1z, gz, bez, wseg,
                                  (float)N, ws);
    k_loss<<<grid_l, 256, 0, stream>>>(
        feat, coord, segm, inst, cent,
        (const unsigned short*)(ws + OFF_W1XS),
        (const unsigned short*)(ws + OFF_W1ZS),
        (const unsigned short*)(ws + OFF_WSEGS),
        ws + OFF_SHX, ws + OFF_SHZ,
        w2xy, b2xy, w2z, b2z, bseg, N, ntiles, tpb_l,
        ws + OFF_ACC, (float*)d_out);
}

// Round 8
// 464.583 us; speedup vs baseline: 1.6294x; 1.6294x over previous
//
#include <hip/hip_runtime.h>
#include <hip/hip_bf16.h>

// Workspace layout (float indices). [COLSUM..DONE] zeroed by one memset each call.
#define OFF_COLSUM 0        // 64
#define OFF_S      64       // 4096
#define OFF_ACC    4160     // 8 loss accumulators (7 used)
#define OFF_DONE   4168     // 1 (int done-counter)
#define OFF_ZEND   4169     // memset extent (floats)
#define OFF_SHX    4176     // 64 BN shift xy
#define OFF_SHZ    4240     // 64 BN shift z
#define OFF_W1XS   4304     // ushort[4096] (w1_xy^T * sc, bf16, [ch j][k])
#define OFF_W1ZS   6352     // ushort[4096]
#define OFF_WSEGS  8400     // ushort[2048] (w_seg^T bf16, rows 20..31 = 0)

typedef __attribute__((ext_vector_type(8))) short bf16x8;
typedef __attribute__((ext_vector_type(4))) float f32x4;

__device__ __forceinline__ unsigned short f2bfh(float x) {
    __hip_bfloat16 h = __float2bfloat16(x);
    return *reinterpret_cast<unsigned short*>(&h);
}

union BF8 { bf16x8 v; unsigned short u[8]; };

__device__ __forceinline__ void gload_lds16(const void* g, void* l) {
    __builtin_amdgcn_global_load_lds((const __attribute__((address_space(1))) void*)g,
                                     (__attribute__((address_space(3))) void*)l, 16, 0, 0);
}

// Shared staging layout (point-major, swizzled; R4-proven):
//   16B unit i of ftile holds feat[r = i>>4][4*((i&15) ^ (r&15)) .. +3]
//   word addr of F[p][c]:  p*64 + (((c>>2) ^ (p&15)) << 2) + (c&3)

// ---------------- Pass 1: colsum + S = F^T F via MFMA, column-frags ----------------
// EXACT R4 body/config (grid 512, 2 blocks/CU) — measured ~85-90 us, 0 conflicts.
__global__ __launch_bounds__(256, 2) void k_stats(const float* __restrict__ feat,
                                                  int N, int ntiles, int tpb,
                                                  float* __restrict__ ws) {
    __shared__ __align__(16) float ftile[2][4096];
    const int t = threadIdx.x;
    const int lane = t & 63, l15 = lane & 15, grp = lane >> 4, wv = t >> 6;

    const f32x4 z4 = {0.f, 0.f, 0.f, 0.f};
    f32x4 acc[4] = {z4, z4, z4, z4};
    float csum = 0.f;

    const int l3 = l15 & 3;
    const int cb_base = l15 >> 2;   // c>>2 = g*4 + cb_base
    const int g1x8 = (grp & 1) * 8; // p&15 = g1x8 | kk

    const int ti0 = blockIdx.x * tpb;
    const int tiend = min(ti0 + tpb, ntiles);

    auto stage = [&](int bufi, int ti) {
        const int row0 = ti * 64;
        if (row0 + 64 <= N) {
#pragma unroll
            for (int c = 0; c < 4; c++) {
                const int r = (wv * 4 + c) * 4 + grp;
                const int u = l15 ^ (r & 15);
                gload_lds16(&feat[(size_t)(row0 + r) * 64 + u * 4],
                            &ftile[bufi][(wv * 4 + c) * 256]);
            }
        } else {
#pragma unroll
            for (int u2 = 0; u2 < 4; u2++) {
                const int i = t + u2 * 256;
                const int r = i >> 4, u = (i & 15) ^ (r & 15);
                float4 v = make_float4(0.f, 0.f, 0.f, 0.f);
                if (row0 + r < N) v = *(const float4*)&feat[(size_t)(row0 + r) * 64 + u * 4];
                *(float4*)&ftile[bufi][i * 4] = v;
            }
        }
    };

    if (ti0 < tiend) stage(0, ti0);
    int cur = 0;
    for (int ti = ti0; ti < tiend; ++ti) {
        __syncthreads();                      // drains staging vmcnt; prev reads done
        if (ti + 1 < tiend) stage(cur ^ 1, ti + 1);
        const float* fb = ftile[cur];

        // column frags: fr[s][h] lane(grp,l15) = F[h*32+grp*8+kk][g*16+l15], g=(wv+s)&3
        bf16x8 fr[4][2];
#pragma unroll
        for (int s = 0; s < 4; s++) {
            const int g = (wv + s) & 3;
            const int cb = (g * 4 + cb_base) ^ g1x8;
#pragma unroll
            for (int h = 0; h < 2; h++) {
                const int pbase = h * 32 + grp * 8;
                float vs[8];
#pragma unroll
                for (int kk = 0; kk < 8; kk++)
                    vs[kk] = fb[(pbase + kk) * 64 + ((cb ^ kk) << 2) + l3];
                BF8 fv;
#pragma unroll
                for (int kk = 0; kk < 8; kk++) fv.u[kk] = f2bfh(vs[kk]);
                fr[s][h] = fv.v;
                if (s == 0) {
#pragma unroll
                    for (int kk = 0; kk < 8; kk++) csum += vs[kk];
                }
            }
        }
        // D = F^T(g=wv rows) * F(g=(wv+s) cols); frag doubles as A and B
#pragma unroll
        for (int s = 0; s < 4; s++) {
            acc[s] = __builtin_amdgcn_mfma_f32_16x16x32_bf16(fr[0][0], fr[s][0], acc[s], 0, 0, 0);
            acc[s] = __builtin_amdgcn_mfma_f32_16x16x32_bf16(fr[0][1], fr[s][1], acc[s], 0, 0, 0);
        }
        cur ^= 1;
    }

    // S[row = wv*16 + grp*4 + r][col = ((wv+s)&3)*16 + l15]
    float* S = ws + OFF_S;
#pragma unroll
    for (int s = 0; s < 4; s++) {
        const int gj = (wv + s) & 3;
#pragma unroll
        for (int r = 0; r < 4; r++)
            atomicAdd(&S[(wv * 16 + grp * 4 + r) * 64 + gj * 16 + l15], acc[s][r]);
    }
    // colsum of channel wv*16 + l15: lane holds its grp's 16 points; reduce over grp
    csum += __shfl_xor(csum, 16);
    csum += __shfl_xor(csum, 32);
    if (grp == 0) atomicAdd(&ws[OFF_COLSUM + wv * 16 + l15], csum);
}

// ------------- Prep: BN scale/shift; scaled bf16 weights (R4-proven) -------------
__global__ __launch_bounds__(256) void k_prep(
    const float* __restrict__ w1xy, const float* __restrict__ b1xy,
    const float* __restrict__ gxy,  const float* __restrict__ bexy,
    const float* __restrict__ w1z,  const float* __restrict__ b1z,
    const float* __restrict__ gz,   const float* __restrict__ bez,
    const float* __restrict__ wseg, float Nf, float* __restrict__ ws) {
    __shared__ float S[64][64];
    __shared__ float cs[64];
    const int t = threadIdx.x;

    for (int i = t; i < 4096; i += 256) ((float*)S)[i] = ws[OFF_S + i];
    if (t < 64) cs[t] = ws[OFF_COLSUM + t];
    __syncthreads();

    if (t < 128) {
        const int head = t >> 6, j = t & 63;
        const float* w1 = head ? w1z : w1xy;
        float w[64];
#pragma unroll
        for (int k = 0; k < 64; k++) w[k] = w1[k * 64 + j];
        float d = 0.f;
#pragma unroll
        for (int k = 0; k < 64; k++) d = fmaf(cs[k], w[k], d);
        float quad = 0.f;
#pragma unroll
        for (int k = 0; k < 64; k++) {
            float rd = 0.f;
#pragma unroll
            for (int l = 0; l < 64; l++) rd = fmaf(S[k][l], w[l], rd);
            quad = fmaf(w[k], rd, quad);
        }
        const float b1 = head ? b1z[j] : b1xy[j];
        const float mu  = d / Nf + b1;
        const float eh2 = quad / Nf + 2.f * b1 * d / Nf + b1 * b1;
        const float var = eh2 - mu * mu;
        const float g  = head ? gz[j]  : gxy[j];
        const float be = head ? bez[j] : bexy[j];
        const float sc = g * rsqrtf(var + 1e-3f);
        const float sh = be - mu * sc;
        ws[(head ? OFF_SHZ : OFF_SHX) + j] = sh;
        unsigned short* dst = (unsigned short*)(ws + (head ? OFF_W1ZS : OFF_W1XS));
#pragma unroll
        for (int k = 0; k < 64; k++) dst[j * 64 + k] = f2bfh(w[k] * sc);
    } else if (t < 160) {
        const int j = t - 128;  // 0..31
        unsigned short* dst = (unsigned short*)(ws + OFF_WSEGS);
        for (int k = 0; k < 64; k++)
            dst[j * 64 + k] = (j < 20) ? f2bfh(wseg[k * 20 + j]) : (unsigned short)0;
    }
}

// ---------------- Pass 2: swapped-operand MFMA heads + lane-local tail + finalize ----------------
// Single change this round: 4 blocks/CU (grid 1024, launch_bounds(256,4)).
__global__ __launch_bounds__(256, 4) void k_loss(
    const float* __restrict__ feat, const float* __restrict__ coord,
    const int* __restrict__ seg, const int* __restrict__ inst,
    const float* __restrict__ cent,
    const unsigned short* __restrict__ w1xs, const unsigned short* __restrict__ w1zs,
    const unsigned short* __restrict__ wsegs,
    const float* __restrict__ shxv, const float* __restrict__ shzv,
    const float* __restrict__ w2xy, const float* __restrict__ b2xy,
    const float* __restrict__ w2z,  const float* __restrict__ b2z,
    const float* __restrict__ bseg,
    int N, int ntiles, int tpb, float* __restrict__ acc, float* __restrict__ out) {
    __shared__ __align__(16) float ftile[2][4096];
    __shared__ float red[4][8];

    const int t = threadIdx.x;
    const int lane = t & 63, l15 = lane & 15, grp = lane >> 4, wv = t >> 6;

    // loop-invariant weight A-frags in VGPRs
    bf16x8 ax[4][2], az[4][2], ag[2][2];
#pragma unroll
    for (int nt = 0; nt < 4; nt++)
#pragma unroll
        for (int h = 0; h < 2; h++) {
            ax[nt][h] = *(const bf16x8*)&w1xs[(nt * 16 + l15) * 64 + grp * 8 + h * 32];
            az[nt][h] = *(const bf16x8*)&w1zs[(nt * 16 + l15) * 64 + grp * 8 + h * 32];
        }
#pragma unroll
    for (int nt = 0; nt < 2; nt++)
#pragma unroll
        for (int h = 0; h < 2; h++)
            ag[nt][h] = *(const bf16x8*)&wsegs[(nt * 16 + l15) * 64 + grp * 8 + h * 32];

    // per-lane constants: channel c = nt*16 + grp*4 + r
    float shx_c[4][4], shz_c[4][4], w20[4][4], w21[4][4], w2zc[4][4], bs_c[2][4];
#pragma unroll
    for (int nt = 0; nt < 4; nt++)
#pragma unroll
        for (int r = 0; r < 4; r++) {
            const int c = nt * 16 + grp * 4 + r;
            shx_c[nt][r] = shxv[c]; shz_c[nt][r] = shzv[c];
            w20[nt][r] = w2xy[c * 2]; w21[nt][r] = w2xy[c * 2 + 1];
            w2zc[nt][r] = w2z[c];
        }
#pragma unroll
    for (int nt = 0; nt < 2; nt++)
#pragma unroll
        for (int r = 0; r < 4; r++) {
            const int c = nt * 16 + grp * 4 + r;
            bs_c[nt][r] = (c < 20) ? bseg[c] : -1e30f;
        }
    const float pb0 = b2xy[0], pb1 = b2xy[1], pbz = b2z[0];

    float s_nll = 0.f, s_vf = 0.f, s_l1xy = 0.f, s_cosxy = 0.f;
    float s_l1z = 0.f, s_cosz = 0.f, s_mask = 0.f;

    const int ti0 = blockIdx.x * tpb;
    const int tiend = min(ti0 + tpb, ntiles);

    auto stage = [&](int bufi, int ti) {
        const int row0 = ti * 64;
        if (row0 + 64 <= N) {
#pragma unroll
            for (int c = 0; c < 4; c++) {
                const int r = (wv * 4 + c) * 4 + grp;
                const int u = l15 ^ (r & 15);
                gload_lds16(&feat[(size_t)(row0 + r) * 64 + u * 4],
                            &ftile[bufi][(wv * 4 + c) * 256]);
            }
        } else {
#pragma unroll
            for (int u2 = 0; u2 < 4; u2++) {
                const int i = t + u2 * 256;
                const int r = i >> 4, u = (i & 15) ^ (r & 15);
                float4 v = make_float4(0.f, 0.f, 0.f, 0.f);
                if (row0 + r < N) v = *(const float4*)&feat[(size_t)(row0 + r) * 64 + u * 4];
                *(float4*)&ftile[bufi][i * 4] = v;
            }
        }
    };

    // point-scalar prefetch one tile ahead
    int p_tg = -1, p_iv = -1;
    float p_c0 = 0.f, p_c1 = 0.f, p_c2 = 0.f, p_e0 = 0.f, p_e1 = 0.f, p_e2 = 0.f;
    auto ptload = [&](int ti) {
        const int gp = ti * 64 + wv * 16 + l15;
        const bool inb = (gp < N);
        p_tg = inb ? seg[gp] : -1;
        p_iv = inb ? inst[gp] : -1;
        if (inb) {
            p_c0 = coord[(size_t)gp * 3]; p_c1 = coord[(size_t)gp * 3 + 1]; p_c2 = coord[(size_t)gp * 3 + 2];
            p_e0 = cent[(size_t)gp * 3];  p_e1 = cent[(size_t)gp * 3 + 1];  p_e2 = cent[(size_t)gp * 3 + 2];
        } else {
            p_c0 = p_c1 = p_c2 = p_e0 = p_e1 = p_e2 = 0.f;
        }
    };

    if (ti0 < tiend) { stage(0, ti0); ptload(ti0); }
    int cur = 0;
    for (int ti = ti0; ti < tiend; ++ti) {
        const int tg = p_tg, iv = p_iv;
        const float c0 = p_c0, c1 = p_c1, c2 = p_c2, e0 = p_e0, e1 = p_e1, e2 = p_e2;

        __syncthreads();
        if (ti + 1 < tiend) { stage(cur ^ 1, ti + 1); ptload(ti + 1); }

        const int p = wv * 16 + l15;
        const float* fb = ftile[cur];
        const float4 q0 = *(const float4*)&fb[(p * 16 + ((grp * 2)     ^ l15)) * 4];
        const float4 q1 = *(const float4*)&fb[(p * 16 + ((grp * 2 + 1) ^ l15)) * 4];
        const float4 q2 = *(const float4*)&fb[(p * 16 + ((8 + grp * 2) ^ l15)) * 4];
        const float4 q3 = *(const float4*)&fb[(p * 16 + ((9 + grp * 2) ^ l15)) * 4];
        BF8 b0, b1;
        b0.u[0] = f2bfh(q0.x); b0.u[1] = f2bfh(q0.y); b0.u[2] = f2bfh(q0.z); b0.u[3] = f2bfh(q0.w);
        b0.u[4] = f2bfh(q1.x); b0.u[5] = f2bfh(q1.y); b0.u[6] = f2bfh(q1.z); b0.u[7] = f2bfh(q1.w);
        b1.u[0] = f2bfh(q2.x); b1.u[1] = f2bfh(q2.y); b1.u[2] = f2bfh(q2.z); b1.u[3] = f2bfh(q2.w);
        b1.u[4] = f2bfh(q3.x); b1.u[5] = f2bfh(q3.y); b1.u[6] = f2bfh(q3.z); b1.u[7] = f2bfh(q3.w);

        // ---- seg head + CE ----
        f32x4 cg0 = {bs_c[0][0], bs_c[0][1], bs_c[0][2], bs_c[0][3]};
        cg0 = __builtin_amdgcn_mfma_f32_16x16x32_bf16(ag[0][0], b0.v, cg0, 0, 0, 0);
        cg0 = __builtin_amdgcn_mfma_f32_16x16x32_bf16(ag[0][1], b1.v, cg0, 0, 0, 0);
        f32x4 cg1 = {bs_c[1][0], bs_c[1][1], bs_c[1][2], bs_c[1][3]};
        cg1 = __builtin_amdgcn_mfma_f32_16x16x32_bf16(ag[1][0], b0.v, cg1, 0, 0, 0);
        cg1 = __builtin_amdgcn_mfma_f32_16x16x32_bf16(ag[1][1], b1.v, cg1, 0, 0, 0);
        float lmax = cg0[0];
#pragma unroll
        for (int r = 1; r < 4; r++) lmax = fmaxf(lmax, cg0[r]);
#pragma unroll
        for (int r = 0; r < 4; r++) lmax = fmaxf(lmax, cg1[r]);
        lmax = fmaxf(lmax, __shfl_xor(lmax, 16));
        lmax = fmaxf(lmax, __shfl_xor(lmax, 32));
        float se = 0.f;
#pragma unroll
        for (int r = 0; r < 4; r++) se += __expf(cg0[r] - lmax);
#pragma unroll
        for (int r = 0; r < 4; r++) se += __expf(cg1[r] - lmax);
        se += __shfl_xor(se, 16); se += __shfl_xor(se, 32);
        const float lse = lmax + __logf(se);
        float lt = 0.f;
#pragma unroll
        for (int r = 0; r < 4; r++) lt += (grp * 4 + r == tg) ? cg0[r] : 0.f;
#pragma unroll
        for (int r = 0; r < 4; r++) lt += (16 + grp * 4 + r == tg) ? cg1[r] : 0.f;
        lt += __shfl_xor(lt, 16); lt += __shfl_xor(lt, 32);
        const float vf = (tg >= 0) ? 1.f : 0.f;
        s_nll += (lse - lt) * vf;
        s_vf += vf;

        // ---- xy + z heads (scale folded into weights, shift via C-init) ----
        float s0 = 0.f, s1 = 0.f, szv = 0.f;
#pragma unroll
        for (int nt = 0; nt < 4; nt++) {
            f32x4 cc = {shx_c[nt][0], shx_c[nt][1], shx_c[nt][2], shx_c[nt][3]};
            cc = __builtin_amdgcn_mfma_f32_16x16x32_bf16(ax[nt][0], b0.v, cc, 0, 0, 0);
            cc = __builtin_amdgcn_mfma_f32_16x16x32_bf16(ax[nt][1], b1.v, cc, 0, 0, 0);
#pragma unroll
            for (int r = 0; r < 4; r++) {
                const float hx = fmaxf(cc[r], 0.f);
                s0 = fmaf(hx, w20[nt][r], s0);
                s1 = fmaf(hx, w21[nt][r], s1);
            }
            f32x4 cz = {shz_c[nt][0], shz_c[nt][1], shz_c[nt][2], shz_c[nt][3]};
            cz = __builtin_amdgcn_mfma_f32_16x16x32_bf16(az[nt][0], b0.v, cz, 0, 0, 0);
            cz = __builtin_amdgcn_mfma_f32_16x16x32_bf16(az[nt][1], b1.v, cz, 0, 0, 0);
#pragma unroll
            for (int r = 0; r < 4; r++) {
                const float hz = fmaxf(cz[r], 0.f);
                szv = fmaf(hz, w2zc[nt][r], szv);
            }
        }
        s0 += __shfl_xor(s0, 16);  s0 += __shfl_xor(s0, 32);
        s1 += __shfl_xor(s1, 16);  s1 += __shfl_xor(s1, 32);
        szv += __shfl_xor(szv, 16); szv += __shfl_xor(szv, 32);
        const float p0 = s0 + pb0, p1 = s1 + pb1, pz = szv + pbz;

        const float mk = (iv >= 0) ? 1.f : 0.f;
        const float a0 = e0 - c0, a1 = e1 - c1, a2 = e2 - c2;
        s_l1xy += (fabsf(a0 - p0) + fabsf(a1 - p1)) * mk;
        const float na = sqrtf(a0 * a0 + a1 * a1) + 1e-8f;
        const float nb = sqrtf(p0 * p0 + p1 * p1) + 1e-8f;
        s_cosxy -= ((a0 * p0 + a1 * p1) / (na * nb)) * mk;
        s_l1z += fabsf(a2 - pz) * mk;
        const float naz = fabsf(a2) + 1e-8f, nbz = fabsf(pz) + 1e-8f;
        s_cosz -= ((a2 * pz) / (naz * nbz)) * mk;
        s_mask += mk;

        cur ^= 1;
    }

    // block reduction; values replicated x4 across grp -> scale 0.25
    float v[7] = {s_nll * 0.25f, s_vf * 0.25f, s_l1xy * 0.25f, s_cosxy * 0.25f,
                  s_l1z * 0.25f, s_cosz * 0.25f, s_mask * 0.25f};
#pragma unroll
    for (int i = 0; i < 7; i++) {
#pragma unroll
        for (int o = 32; o > 0; o >>= 1) v[i] += __shfl_down(v[i], o);
    }
    if (lane == 0) {
#pragma unroll
        for (int i = 0; i < 7; i++) red[wv][i] = v[i];
    }
    __syncthreads();
    if (t < 7) {
        float s = red[0][t] + red[1][t] + red[2][t] + red[3][t];
        atomicAdd(&acc[t], s);
    }
    __syncthreads();   // drains the acc atomics before the done handshake
    if (t == 0) {
        __threadfence();
        int* done = (int*)(acc + (OFF_DONE - OFF_ACC));
        if (atomicAdd(done, 1) == (int)gridDim.x - 1) {
            __threadfence();
            float sv[7];
#pragma unroll
            for (int i = 0; i < 7; i++) sv[i] = atomicAdd(&acc[i], 0.f);
            const float segl = sv[0] / sv[1];
            const float den = sv[6] + 1e-8f;
            const float l1xy = sv[2] / den, cosxy = sv[3] / den;
            const float l1z = sv[4] / den, cosz = sv[5] / den;
            out[0] = segl + l1xy + l1xy + 0.5f * (l1z + cosz);
            out[1] = segl;
            out[2] = l1xy;
            out[3] = cosxy;
            out[4] = l1z;
            out[5] = cosz;
        }
    }
}

extern "C" void kernel_launch(void* const* d_in, const int* in_sizes, int n_in,
                              void* d_out, int out_size, void* d_ws, size_t ws_size,
                              hipStream_t stream) {
    const float* feat  = (const float*)d_in[0];
    const float* coord = (const float*)d_in[1];
    const int*   segm  = (const int*)d_in[2];
    const int*   inst  = (const int*)d_in[3];
    const float* cent  = (const float*)d_in[4];
    const float* w1xy  = (const float*)d_in[5];
    const float* b1xy  = (const float*)d_in[6];
    const float* gxy   = (const float*)d_in[7];
    const float* bexy  = (const float*)d_in[8];
    const float* w2xy  = (const float*)d_in[9];
    const float* b2xy  = (const float*)d_in[10];
    const float* w1z   = (const float*)d_in[11];
    const float* b1z   = (const float*)d_in[12];
    const float* gz    = (const float*)d_in[13];
    const float* bez   = (const float*)d_in[14];
    const float* w2z   = (const float*)d_in[15];
    const float* b2z   = (const float*)d_in[16];
    const float* wseg  = (const float*)d_in[17];
    const float* bseg  = (const float*)d_in[18];

    const int N = in_sizes[0] / 64;
    float* ws = (float*)d_ws;
    const int ntiles = (N + 63) >> 6;

    const int grid_s = 512;
    const int tpb_s = (ntiles + grid_s - 1) / grid_s;
    const int grid_l = 1024;
    const int tpb_l = (ntiles + grid_l - 1) / grid_l;

    hipMemsetAsync(d_ws, 0, OFF_ZEND * sizeof(float), stream);

    k_stats<<<grid_s, 256, 0, stream>>>(feat, N, ntiles, tpb_s, ws);
    k_prep<<<1, 256, 0, stream>>>(w1xy, b1xy, gxy, bexy, w1z, b1z, gz, bez, wseg,
                                  (float)N, ws);
    k_loss<<<grid_l, 256, 0, stream>>>(
        feat, coord, segm, inst, cent,
        (const unsigned short*)(ws + OFF_W1XS),
        (const unsigned short*)(ws + OFF_W1ZS),
        (const unsigned short*)(ws + OFF_WSEGS),
        ws + OFF_SHX, ws + OFF_SHZ,
        w2xy, b2xy, w2z, b2z, bseg, N, ntiles, tpb_l,
        ws + OFF_ACC, (float*)d_out);
}

// Round 9
// 354.901 us; speedup vs baseline: 2.1329x; 1.3090x over previous
//
#include <hip/hip_runtime.h>
#include <hip/hip_bf16.h>

// Workspace layout (float indices). [COLSUM..DONE] zeroed by one memset each call.
#define OFF_COLSUM 0        // 64
#define OFF_S      64       // 4096
#define OFF_ACC    4160     // 8 loss accumulators (7 used)
#define OFF_DONE   4168     // 1 (int done-counter)
#define OFF_ZEND   4169     // memset extent (floats)
#define OFF_SHX    4176     // 64 BN shift xy
#define OFF_SHZ    4240     // 64 BN shift z
#define OFF_W1XS   4304     // ushort[4096] (w1_xy^T * sc, bf16, [ch j][k])
#define OFF_W1ZS   6352     // ushort[4096]
#define OFF_WSEGS  8400     // ushort[2048] (w_seg^T bf16, rows 20..31 = 0)

typedef __attribute__((ext_vector_type(8))) short bf16x8;
typedef __attribute__((ext_vector_type(4))) float f32x4;

__device__ __forceinline__ unsigned short f2bfh(float x) {
    __hip_bfloat16 h = __float2bfloat16(x);
    return *reinterpret_cast<unsigned short*>(&h);
}

union BF8 { bf16x8 v; unsigned short u[8]; };

__device__ __forceinline__ void gload_lds16(const void* g, void* l) {
    __builtin_amdgcn_global_load_lds((const __attribute__((address_space(1))) void*)g,
                                     (__attribute__((address_space(3))) void*)l, 16, 0, 0);
}

// Shared staging layout (point-major, swizzled; R4-proven):
//   16B unit i of ftile holds feat[r = i>>4][4*((i&15) ^ (r&15)) .. +3]

// ---------------- Pass 1: colsum + S = F^T F via MFMA, column-frags ----------------
// EXACT R4 body/config (grid 512, 2 blocks/CU) — measured ~85-90 us, 0 conflicts.
__global__ __launch_bounds__(256, 2) void k_stats(const float* __restrict__ feat,
                                                  int N, int ntiles, int tpb,
                                                  float* __restrict__ ws) {
    __shared__ __align__(16) float ftile[2][4096];
    const int t = threadIdx.x;
    const int lane = t & 63, l15 = lane & 15, grp = lane >> 4, wv = t >> 6;

    const f32x4 z4 = {0.f, 0.f, 0.f, 0.f};
    f32x4 acc[4] = {z4, z4, z4, z4};
    float csum = 0.f;

    const int l3 = l15 & 3;
    const int cb_base = l15 >> 2;   // c>>2 = g*4 + cb_base
    const int g1x8 = (grp & 1) * 8; // p&15 = g1x8 | kk

    const int ti0 = blockIdx.x * tpb;
    const int tiend = min(ti0 + tpb, ntiles);

    auto stage = [&](int bufi, int ti) {
        const int row0 = ti * 64;
        if (row0 + 64 <= N) {
#pragma unroll
            for (int c = 0; c < 4; c++) {
                const int r = (wv * 4 + c) * 4 + grp;
                const int u = l15 ^ (r & 15);
                gload_lds16(&feat[(size_t)(row0 + r) * 64 + u * 4],
                            &ftile[bufi][(wv * 4 + c) * 256]);
            }
        } else {
#pragma unroll
            for (int u2 = 0; u2 < 4; u2++) {
                const int i = t + u2 * 256;
                const int r = i >> 4, u = (i & 15) ^ (r & 15);
                float4 v = make_float4(0.f, 0.f, 0.f, 0.f);
                if (row0 + r < N) v = *(const float4*)&feat[(size_t)(row0 + r) * 64 + u * 4];
                *(float4*)&ftile[bufi][i * 4] = v;
            }
        }
    };

    if (ti0 < tiend) stage(0, ti0);
    int cur = 0;
    for (int ti = ti0; ti < tiend; ++ti) {
        __syncthreads();                      // drains staging vmcnt; prev reads done
        if (ti + 1 < tiend) stage(cur ^ 1, ti + 1);
        const float* fb = ftile[cur];

        // column frags: fr[s][h] lane(grp,l15) = F[h*32+grp*8+kk][g*16+l15], g=(wv+s)&3
        bf16x8 fr[4][2];
#pragma unroll
        for (int s = 0; s < 4; s++) {
            const int g = (wv + s) & 3;
            const int cb = (g * 4 + cb_base) ^ g1x8;
#pragma unroll
            for (int h = 0; h < 2; h++) {
                const int pbase = h * 32 + grp * 8;
                float vs[8];
#pragma unroll
                for (int kk = 0; kk < 8; kk++)
                    vs[kk] = fb[(pbase + kk) * 64 + ((cb ^ kk) << 2) + l3];
                BF8 fv;
#pragma unroll
                for (int kk = 0; kk < 8; kk++) fv.u[kk] = f2bfh(vs[kk]);
                fr[s][h] = fv.v;
                if (s == 0) {
#pragma unroll
                    for (int kk = 0; kk < 8; kk++) csum += vs[kk];
                }
            }
        }
        // D = F^T(g=wv rows) * F(g=(wv+s) cols); frag doubles as A and B
#pragma unroll
        for (int s = 0; s < 4; s++) {
            acc[s] = __builtin_amdgcn_mfma_f32_16x16x32_bf16(fr[0][0], fr[s][0], acc[s], 0, 0, 0);
            acc[s] = __builtin_amdgcn_mfma_f32_16x16x32_bf16(fr[0][1], fr[s][1], acc[s], 0, 0, 0);
        }
        cur ^= 1;
    }

    // S[row = wv*16 + grp*4 + r][col = ((wv+s)&3)*16 + l15]
    float* S = ws + OFF_S;
#pragma unroll
    for (int s = 0; s < 4; s++) {
        const int gj = (wv + s) & 3;
#pragma unroll
        for (int r = 0; r < 4; r++)
            atomicAdd(&S[(wv * 16 + grp * 4 + r) * 64 + gj * 16 + l15], acc[s][r]);
    }
    // colsum of channel wv*16 + l15: lane holds its grp's 16 points; reduce over grp
    csum += __shfl_xor(csum, 16);
    csum += __shfl_xor(csum, 32);
    if (grp == 0) atomicAdd(&ws[OFF_COLSUM + wv * 16 + l15], csum);
}

// ------------- Prep: BN scale/shift; scaled bf16 weights (R4-proven) -------------
__global__ __launch_bounds__(256) void k_prep(
    const float* __restrict__ w1xy, const float* __restrict__ b1xy,
    const float* __restrict__ gxy,  const float* __restrict__ bexy,
    const float* __restrict__ w1z,  const float* __restrict__ b1z,
    const float* __restrict__ gz,   const float* __restrict__ bez,
    const float* __restrict__ wseg, float Nf, float* __restrict__ ws) {
    __shared__ float S[64][64];
    __shared__ float cs[64];
    const int t = threadIdx.x;

    for (int i = t; i < 4096; i += 256) ((float*)S)[i] = ws[OFF_S + i];
    if (t < 64) cs[t] = ws[OFF_COLSUM + t];
    __syncthreads();

    if (t < 128) {
        const int head = t >> 6, j = t & 63;
        const float* w1 = head ? w1z : w1xy;
        float w[64];
#pragma unroll
        for (int k = 0; k < 64; k++) w[k] = w1[k * 64 + j];
        float d = 0.f;
#pragma unroll
        for (int k = 0; k < 64; k++) d = fmaf(cs[k], w[k], d);
        float quad = 0.f;
#pragma unroll
        for (int k = 0; k < 64; k++) {
            float rd = 0.f;
#pragma unroll
            for (int l = 0; l < 64; l++) rd = fmaf(S[k][l], w[l], rd);
            quad = fmaf(w[k], rd, quad);
        }
        const float b1 = head ? b1z[j] : b1xy[j];
        const float mu  = d / Nf + b1;
        const float eh2 = quad / Nf + 2.f * b1 * d / Nf + b1 * b1;
        const float var = eh2 - mu * mu;
        const float g  = head ? gz[j]  : gxy[j];
        const float be = head ? bez[j] : bexy[j];
        const float sc = g * rsqrtf(var + 1e-3f);
        const float sh = be - mu * sc;
        ws[(head ? OFF_SHZ : OFF_SHX) + j] = sh;
        unsigned short* dst = (unsigned short*)(ws + (head ? OFF_W1ZS : OFF_W1XS));
#pragma unroll
        for (int k = 0; k < 64; k++) dst[j * 64 + k] = f2bfh(w[k] * sc);
    } else if (t < 160) {
        const int j = t - 128;  // 0..31
        unsigned short* dst = (unsigned short*)(ws + OFF_WSEGS);
        for (int k = 0; k < 64; k++)
            dst[j * 64 + k] = (j < 20) ? f2bfh(wseg[k * 20 + j]) : (unsigned short)0;
    }
}

// ---------------- Pass 2: swapped-operand MFMA heads + lane-local tail + finalize ----------------
// Single change this round: LB(256,3), grid 768 (VGPR cap ~170 >= 84 resident — no spill).
__global__ __launch_bounds__(256, 3) void k_loss(
    const float* __restrict__ feat, const float* __restrict__ coord,
    const int* __restrict__ seg, const int* __restrict__ inst,
    const float* __restrict__ cent,
    const unsigned short* __restrict__ w1xs, const unsigned short* __restrict__ w1zs,
    const unsigned short* __restrict__ wsegs,
    const float* __restrict__ shxv, const float* __restrict__ shzv,
    const float* __restrict__ w2xy, const float* __restrict__ b2xy,
    const float* __restrict__ w2z,  const float* __restrict__ b2z,
    const float* __restrict__ bseg,
    int N, int ntiles, int tpb, float* __restrict__ acc, float* __restrict__ out) {
    __shared__ __align__(16) float ftile[2][4096];
    __shared__ float red[4][8];

    const int t = threadIdx.x;
    const int lane = t & 63, l15 = lane & 15, grp = lane >> 4, wv = t >> 6;

    // loop-invariant weight A-frags in VGPRs
    bf16x8 ax[4][2], az[4][2], ag[2][2];
#pragma unroll
    for (int nt = 0; nt < 4; nt++)
#pragma unroll
        for (int h = 0; h < 2; h++) {
            ax[nt][h] = *(const bf16x8*)&w1xs[(nt * 16 + l15) * 64 + grp * 8 + h * 32];
            az[nt][h] = *(const bf16x8*)&w1zs[(nt * 16 + l15) * 64 + grp * 8 + h * 32];
        }
#pragma unroll
    for (int nt = 0; nt < 2; nt++)
#pragma unroll
        for (int h = 0; h < 2; h++)
            ag[nt][h] = *(const bf16x8*)&wsegs[(nt * 16 + l15) * 64 + grp * 8 + h * 32];

    // per-lane constants: channel c = nt*16 + grp*4 + r
    float shx_c[4][4], shz_c[4][4], w20[4][4], w21[4][4], w2zc[4][4], bs_c[2][4];
#pragma unroll
    for (int nt = 0; nt < 4; nt++)
#pragma unroll
        for (int r = 0; r < 4; r++) {
            const int c = nt * 16 + grp * 4 + r;
            shx_c[nt][r] = shxv[c]; shz_c[nt][r] = shzv[c];
            w20[nt][r] = w2xy[c * 2]; w21[nt][r] = w2xy[c * 2 + 1];
            w2zc[nt][r] = w2z[c];
        }
#pragma unroll
    for (int nt = 0; nt < 2; nt++)
#pragma unroll
        for (int r = 0; r < 4; r++) {
            const int c = nt * 16 + grp * 4 + r;
            bs_c[nt][r] = (c < 20) ? bseg[c] : -1e30f;
        }
    const float pb0 = b2xy[0], pb1 = b2xy[1], pbz = b2z[0];

    float s_nll = 0.f, s_vf = 0.f, s_l1xy = 0.f, s_cosxy = 0.f;
    float s_l1z = 0.f, s_cosz = 0.f, s_mask = 0.f;

    const int ti0 = blockIdx.x * tpb;
    const int tiend = min(ti0 + tpb, ntiles);

    auto stage = [&](int bufi, int ti) {
        const int row0 = ti * 64;
        if (row0 + 64 <= N) {
#pragma unroll
            for (int c = 0; c < 4; c++) {
                const int r = (wv * 4 + c) * 4 + grp;
                const int u = l15 ^ (r & 15);
                gload_lds16(&feat[(size_t)(row0 + r) * 64 + u * 4],
                            &ftile[bufi][(wv * 4 + c) * 256]);
            }
        } else {
#pragma unroll
            for (int u2 = 0; u2 < 4; u2++) {
                const int i = t + u2 * 256;
                const int r = i >> 4, u = (i & 15) ^ (r & 15);
                float4 v = make_float4(0.f, 0.f, 0.f, 0.f);
                if (row0 + r < N) v = *(const float4*)&feat[(size_t)(row0 + r) * 64 + u * 4];
                *(float4*)&ftile[bufi][i * 4] = v;
            }
        }
    };

    // point-scalar prefetch one tile ahead
    int p_tg = -1, p_iv = -1;
    float p_c0 = 0.f, p_c1 = 0.f, p_c2 = 0.f, p_e0 = 0.f, p_e1 = 0.f, p_e2 = 0.f;
    auto ptload = [&](int ti) {
        const int gp = ti * 64 + wv * 16 + l15;
        const bool inb = (gp < N);
        p_tg = inb ? seg[gp] : -1;
        p_iv = inb ? inst[gp] : -1;
        if (inb) {
            p_c0 = coord[(size_t)gp * 3]; p_c1 = coord[(size_t)gp * 3 + 1]; p_c2 = coord[(size_t)gp * 3 + 2];
            p_e0 = cent[(size_t)gp * 3];  p_e1 = cent[(size_t)gp * 3 + 1];  p_e2 = cent[(size_t)gp * 3 + 2];
        } else {
            p_c0 = p_c1 = p_c2 = p_e0 = p_e1 = p_e2 = 0.f;
        }
    };

    if (ti0 < tiend) { stage(0, ti0); ptload(ti0); }
    int cur = 0;
    for (int ti = ti0; ti < tiend; ++ti) {
        const int tg = p_tg, iv = p_iv;
        const float c0 = p_c0, c1 = p_c1, c2 = p_c2, e0 = p_e0, e1 = p_e1, e2 = p_e2;

        __syncthreads();
        if (ti + 1 < tiend) { stage(cur ^ 1, ti + 1); ptload(ti + 1); }

        const int p = wv * 16 + l15;
        const float* fb = ftile[cur];
        const float4 q0 = *(const float4*)&fb[(p * 16 + ((grp * 2)     ^ l15)) * 4];
        const float4 q1 = *(const float4*)&fb[(p * 16 + ((grp * 2 + 1) ^ l15)) * 4];
        const float4 q2 = *(const float4*)&fb[(p * 16 + ((8 + grp * 2) ^ l15)) * 4];
        const float4 q3 = *(const float4*)&fb[(p * 16 + ((9 + grp * 2) ^ l15)) * 4];
        BF8 b0, b1;
        b0.u[0] = f2bfh(q0.x); b0.u[1] = f2bfh(q0.y); b0.u[2] = f2bfh(q0.z); b0.u[3] = f2bfh(q0.w);
        b0.u[4] = f2bfh(q1.x); b0.u[5] = f2bfh(q1.y); b0.u[6] = f2bfh(q1.z); b0.u[7] = f2bfh(q1.w);
        b1.u[0] = f2bfh(q2.x); b1.u[1] = f2bfh(q2.y); b1.u[2] = f2bfh(q2.z); b1.u[3] = f2bfh(q2.w);
        b1.u[4] = f2bfh(q3.x); b1.u[5] = f2bfh(q3.y); b1.u[6] = f2bfh(q3.z); b1.u[7] = f2bfh(q3.w);

        // ---- seg head + CE ----
        f32x4 cg0 = {bs_c[0][0], bs_c[0][1], bs_c[0][2], bs_c[0][3]};
        cg0 = __builtin_amdgcn_mfma_f32_16x16x32_bf16(ag[0][0], b0.v, cg0, 0, 0, 0);
        cg0 = __builtin_amdgcn_mfma_f32_16x16x32_bf16(ag[0][1], b1.v, cg0, 0, 0, 0);
        f32x4 cg1 = {bs_c[1][0], bs_c[1][1], bs_c[1][2], bs_c[1][3]};
        cg1 = __builtin_amdgcn_mfma_f32_16x16x32_bf16(ag[1][0], b0.v, cg1, 0, 0, 0);
        cg1 = __builtin_amdgcn_mfma_f32_16x16x32_bf16(ag[1][1], b1.v, cg1, 0, 0, 0);
        float lmax = cg0[0];
#pragma unroll
        for (int r = 1; r < 4; r++) lmax = fmaxf(lmax, cg0[r]);
#pragma unroll
        for (int r = 0; r < 4; r++) lmax = fmaxf(lmax, cg1[r]);
        lmax = fmaxf(lmax, __shfl_xor(lmax, 16));
        lmax = fmaxf(lmax, __shfl_xor(lmax, 32));
        float se = 0.f;
#pragma unroll
        for (int r = 0; r < 4; r++) se += __expf(cg0[r] - lmax);
#pragma unroll
        for (int r = 0; r < 4; r++) se += __expf(cg1[r] - lmax);
        se += __shfl_xor(se, 16); se += __shfl_xor(se, 32);
        const float lse = lmax + __logf(se);
        float lt = 0.f;
#pragma unroll
        for (int r = 0; r < 4; r++) lt += (grp * 4 + r == tg) ? cg0[r] : 0.f;
#pragma unroll
        for (int r = 0; r < 4; r++) lt += (16 + grp * 4 + r == tg) ? cg1[r] : 0.f;
        lt += __shfl_xor(lt, 16); lt += __shfl_xor(lt, 32);
        const float vf = (tg >= 0) ? 1.f : 0.f;
        s_nll += (lse - lt) * vf;
        s_vf += vf;

        // ---- xy + z heads (scale folded into weights, shift via C-init) ----
        float s0 = 0.f, s1 = 0.f, szv = 0.f;
#pragma unroll
        for (int nt = 0; nt < 4; nt++) {
            f32x4 cc = {shx_c[nt][0], shx_c[nt][1], shx_c[nt][2], shx_c[nt][3]};
            cc = __builtin_amdgcn_mfma_f32_16x16x32_bf16(ax[nt][0], b0.v, cc, 0, 0, 0);
            cc = __builtin_amdgcn_mfma_f32_16x16x32_bf16(ax[nt][1], b1.v, cc, 0, 0, 0);
#pragma unroll
            for (int r = 0; r < 4; r++) {
                const float hx = fmaxf(cc[r], 0.f);
                s0 = fmaf(hx, w20[nt][r], s0);
                s1 = fmaf(hx, w21[nt][r], s1);
            }
            f32x4 cz = {shz_c[nt][0], shz_c[nt][1], shz_c[nt][2], shz_c[nt][3]};
            cz = __builtin_amdgcn_mfma_f32_16x16x32_bf16(az[nt][0], b0.v, cz, 0, 0, 0);
            cz = __builtin_amdgcn_mfma_f32_16x16x32_bf16(az[nt][1], b1.v, cz, 0, 0, 0);
#pragma unroll
            for (int r = 0; r < 4; r++) {
                const float hz = fmaxf(cz[r], 0.f);
                szv = fmaf(hz, w2zc[nt][r], szv);
            }
        }
        s0 += __shfl_xor(s0, 16);  s0 += __shfl_xor(s0, 32);
        s1 += __shfl_xor(s1, 16);  s1 += __shfl_xor(s1, 32);
        szv += __shfl_xor(szv, 16); szv += __shfl_xor(szv, 32);
        const float p0 = s0 + pb0, p1 = s1 + pb1, pz = szv + pbz;

        const float mk = (iv >= 0) ? 1.f : 0.f;
        const float a0 = e0 - c0, a1 = e1 - c1, a2 = e2 - c2;
        s_l1xy += (fabsf(a0 - p0) + fabsf(a1 - p1)) * mk;
        const float na = sqrtf(a0 * a0 + a1 * a1) + 1e-8f;
        const float nb = sqrtf(p0 * p0 + p1 * p1) + 1e-8f;
        s_cosxy -= ((a0 * p0 + a1 * p1) / (na * nb)) * mk;
        s_l1z += fabsf(a2 - pz) * mk;
        const float naz = fabsf(a2) + 1e-8f, nbz = fabsf(pz) + 1e-8f;
        s_cosz -= ((a2 * pz) / (naz * nbz)) * mk;
        s_mask += mk;

        cur ^= 1;
    }

    // block reduction; values replicated x4 across grp -> scale 0.25
    float v[7] = {s_nll * 0.25f, s_vf * 0.25f, s_l1xy * 0.25f, s_cosxy * 0.25f,
                  s_l1z * 0.25f, s_cosz * 0.25f, s_mask * 0.25f};
#pragma unroll
    for (int i = 0; i < 7; i++) {
#pragma unroll
        for (int o = 32; o > 0; o >>= 1) v[i] += __shfl_down(v[i], o);
    }
    if (lane == 0) {
#pragma unroll
        for (int i = 0; i < 7; i++) red[wv][i] = v[i];
    }
    __syncthreads();
    if (t < 7) {
        float s = red[0][t] + red[1][t] + red[2][t] + red[3][t];
        atomicAdd(&acc[t], s);
    }
    __syncthreads();   // drains the acc atomics before the done handshake
    if (t == 0) {
        __threadfence();
        int* done = (int*)(acc + (OFF_DONE - OFF_ACC));
        if (atomicAdd(done, 1) == (int)gridDim.x - 1) {
            __threadfence();
            float sv[7];
#pragma unroll
            for (int i = 0; i < 7; i++) sv[i] = atomicAdd(&acc[i], 0.f);
            const float segl = sv[0] / sv[1];
            const float den = sv[6] + 1e-8f;
            const float l1xy = sv[2] / den, cosxy = sv[3] / den;
            const float l1z = sv[4] / den, cosz = sv[5] / den;
            out[0] = segl + l1xy + l1xy + 0.5f * (l1z + cosz);
            out[1] = segl;
            out[2] = l1xy;
            out[3] = cosxy;
            out[4] = l1z;
            out[5] = cosz;
        }
    }
}

extern "C" void kernel_launch(void* const* d_in, const int* in_sizes, int n_in,
                              void* d_out, int out_size, void* d_ws, size_t ws_size,
                              hipStream_t stream) {
    const float* feat  = (const float*)d_in[0];
    const float* coord = (const float*)d_in[1];
    const int*   segm  = (const int*)d_in[2];
    const int*   inst  = (const int*)d_in[3];
    const float* cent  = (const float*)d_in[4];
    const float* w1xy  = (const float*)d_in[5];
    const float* b1xy  = (const float*)d_in[6];
    const float* gxy   = (const float*)d_in[7];
    const float* bexy  = (const float*)d_in[8];
    const float* w2xy  = (const float*)d_in[9];
    const float* b2xy  = (const float*)d_in[10];
    const float* w1z   = (const float*)d_in[11];
    const float* b1z   = (const float*)d_in[12];
    const float* gz    = (const float*)d_in[13];
    const float* bez   = (const float*)d_in[14];
    const float* w2z   = (const float*)d_in[15];
    const float* b2z   = (const float*)d_in[16];
    const float* wseg  = (const float*)d_in[17];
    const float* bseg  = (const float*)d_in[18];

    const int N = in_sizes[0] / 64;
    float* ws = (float*)d_ws;
    const int ntiles = (N + 63) >> 6;

    const int grid_s = 512;
    const int tpb_s = (ntiles + grid_s - 1) / grid_s;
    const int grid_l = 768;
    const int tpb_l = (ntiles + grid_l - 1) / grid_l;

    hipMemsetAsync(d_ws, 0, OFF_ZEND * sizeof(float), stream);

    k_stats<<<grid_s, 256, 0, stream>>>(feat, N, ntiles, tpb_s, ws);
    k_prep<<<1, 256, 0, stream>>>(w1xy, b1xy, gxy, bexy, w1z, b1z, gz, bez, wseg,
                                  (float)N, ws);
    k_loss<<<grid_l, 256, 0, stream>>>(
        feat, coord, segm, inst, cent,
        (const unsigned short*)(ws + OFF_W1XS),
        (const unsigned short*)(ws + OFF_W1ZS),
        (const unsigned short*)(ws + OFF_WSEGS),
        ws + OFF_SHX, ws + OFF_SHZ,
        w2xy, b2xy, w2z, b2z, bseg, N, ntiles, tpb_l,
        ws + OFF_ACC, (float*)d_out);
}

// Round 10
// 226.759 us; speedup vs baseline: 3.3383x; 1.5651x over previous
//
#include <hip/hip_runtime.h>
#include <hip/hip_bf16.h>

// Workspace layout (float indices). [COLSUM..DONE] zeroed by one memset each call.
#define OFF_COLSUM 0        // 64
#define OFF_S      64       // 4096
#define OFF_ACC    4160     // 8 loss accumulators (7 used)
#define OFF_DONE   4168     // 1 (int done-counter)
#define OFF_ZEND   4169     // memset extent (floats)
#define OFF_SHX    4176     // 64 BN shift xy
#define OFF_SHZ    4240     // 64 BN shift z
#define OFF_W1XS   4304     // ushort[4096] (w1_xy^T * sc, bf16, [ch j][k])
#define OFF_W1ZS   6352     // ushort[4096]
#define OFF_WSEGS  8400     // ushort[2048] (w_seg^T bf16, rows 20..31 = 0)

typedef __attribute__((ext_vector_type(8))) short bf16x8;
typedef __attribute__((ext_vector_type(4))) float f32x4;

__device__ __forceinline__ unsigned short f2bfh(float x) {
    __hip_bfloat16 h = __float2bfloat16(x);
    return *reinterpret_cast<unsigned short*>(&h);
}

union BF8 { bf16x8 v; unsigned short u[8]; };

__device__ __forceinline__ void gload_lds16(const void* g, void* l) {
    __builtin_amdgcn_global_load_lds((const __attribute__((address_space(1))) void*)g,
                                     (__attribute__((address_space(3))) void*)l, 16, 0, 0);
}

// Shared staging layout (point-major, swizzled; R4-proven):
//   16B unit i of ftile holds feat[r = i>>4][4*((i&15) ^ (r&15)) .. +3]

// ---------------- Pass 1: colsum + S = F^T F via MFMA, column-frags ----------------
// EXACT R4 body/config (grid 512, 2 blocks/CU) — measured ~85-90 us, 0 conflicts.
__global__ __launch_bounds__(256, 2) void k_stats(const float* __restrict__ feat,
                                                  int N, int ntiles, int tpb,
                                                  float* __restrict__ ws) {
    __shared__ __align__(16) float ftile[2][4096];
    const int t = threadIdx.x;
    const int lane = t & 63, l15 = lane & 15, grp = lane >> 4, wv = t >> 6;

    const f32x4 z4 = {0.f, 0.f, 0.f, 0.f};
    f32x4 acc[4] = {z4, z4, z4, z4};
    float csum = 0.f;

    const int l3 = l15 & 3;
    const int cb_base = l15 >> 2;   // c>>2 = g*4 + cb_base
    const int g1x8 = (grp & 1) * 8; // p&15 = g1x8 | kk

    const int ti0 = blockIdx.x * tpb;
    const int tiend = min(ti0 + tpb, ntiles);

    auto stage = [&](int bufi, int ti) {
        const int row0 = ti * 64;
        if (row0 + 64 <= N) {
#pragma unroll
            for (int c = 0; c < 4; c++) {
                const int r = (wv * 4 + c) * 4 + grp;
                const int u = l15 ^ (r & 15);
                gload_lds16(&feat[(size_t)(row0 + r) * 64 + u * 4],
                            &ftile[bufi][(wv * 4 + c) * 256]);
            }
        } else {
#pragma unroll
            for (int u2 = 0; u2 < 4; u2++) {
                const int i = t + u2 * 256;
                const int r = i >> 4, u = (i & 15) ^ (r & 15);
                float4 v = make_float4(0.f, 0.f, 0.f, 0.f);
                if (row0 + r < N) v = *(const float4*)&feat[(size_t)(row0 + r) * 64 + u * 4];
                *(float4*)&ftile[bufi][i * 4] = v;
            }
        }
    };

    if (ti0 < tiend) stage(0, ti0);
    int cur = 0;
    for (int ti = ti0; ti < tiend; ++ti) {
        __syncthreads();                      // drains staging vmcnt; prev reads done
        if (ti + 1 < tiend) stage(cur ^ 1, ti + 1);
        const float* fb = ftile[cur];

        // column frags: fr[s][h] lane(grp,l15) = F[h*32+grp*8+kk][g*16+l15], g=(wv+s)&3
        bf16x8 fr[4][2];
#pragma unroll
        for (int s = 0; s < 4; s++) {
            const int g = (wv + s) & 3;
            const int cb = (g * 4 + cb_base) ^ g1x8;
#pragma unroll
            for (int h = 0; h < 2; h++) {
                const int pbase = h * 32 + grp * 8;
                float vs[8];
#pragma unroll
                for (int kk = 0; kk < 8; kk++)
                    vs[kk] = fb[(pbase + kk) * 64 + ((cb ^ kk) << 2) + l3];
                BF8 fv;
#pragma unroll
                for (int kk = 0; kk < 8; kk++) fv.u[kk] = f2bfh(vs[kk]);
                fr[s][h] = fv.v;
                if (s == 0) {
#pragma unroll
                    for (int kk = 0; kk < 8; kk++) csum += vs[kk];
                }
            }
        }
        // D = F^T(g=wv rows) * F(g=(wv+s) cols); frag doubles as A and B
#pragma unroll
        for (int s = 0; s < 4; s++) {
            acc[s] = __builtin_amdgcn_mfma_f32_16x16x32_bf16(fr[0][0], fr[s][0], acc[s], 0, 0, 0);
            acc[s] = __builtin_amdgcn_mfma_f32_16x16x32_bf16(fr[0][1], fr[s][1], acc[s], 0, 0, 0);
        }
        cur ^= 1;
    }

    // S[row = wv*16 + grp*4 + r][col = ((wv+s)&3)*16 + l15]
    float* S = ws + OFF_S;
#pragma unroll
    for (int s = 0; s < 4; s++) {
        const int gj = (wv + s) & 3;
#pragma unroll
        for (int r = 0; r < 4; r++)
            atomicAdd(&S[(wv * 16 + grp * 4 + r) * 64 + gj * 16 + l15], acc[s][r]);
    }
    // colsum of channel wv*16 + l15: lane holds its grp's 16 points; reduce over grp
    csum += __shfl_xor(csum, 16);
    csum += __shfl_xor(csum, 32);
    if (grp == 0) atomicAdd(&ws[OFF_COLSUM + wv * 16 + l15], csum);
}

// ------------- Prep: BN scale/shift; scaled bf16 weights (R4-proven) -------------
__global__ __launch_bounds__(256) void k_prep(
    const float* __restrict__ w1xy, const float* __restrict__ b1xy,
    const float* __restrict__ gxy,  const float* __restrict__ bexy,
    const float* __restrict__ w1z,  const float* __restrict__ b1z,
    const float* __restrict__ gz,   const float* __restrict__ bez,
    const float* __restrict__ wseg, float Nf, float* __restrict__ ws) {
    __shared__ float S[64][64];
    __shared__ float cs[64];
    const int t = threadIdx.x;

    for (int i = t; i < 4096; i += 256) ((float*)S)[i] = ws[OFF_S + i];
    if (t < 64) cs[t] = ws[OFF_COLSUM + t];
    __syncthreads();

    if (t < 128) {
        const int head = t >> 6, j = t & 63;
        const float* w1 = head ? w1z : w1xy;
        float w[64];
#pragma unroll
        for (int k = 0; k < 64; k++) w[k] = w1[k * 64 + j];
        float d = 0.f;
#pragma unroll
        for (int k = 0; k < 64; k++) d = fmaf(cs[k], w[k], d);
        float quad = 0.f;
#pragma unroll
        for (int k = 0; k < 64; k++) {
            float rd = 0.f;
#pragma unroll
            for (int l = 0; l < 64; l++) rd = fmaf(S[k][l], w[l], rd);
            quad = fmaf(w[k], rd, quad);
        }
        const float b1 = head ? b1z[j] : b1xy[j];
        const float mu  = d / Nf + b1;
        const float eh2 = quad / Nf + 2.f * b1 * d / Nf + b1 * b1;
        const float var = eh2 - mu * mu;
        const float g  = head ? gz[j]  : gxy[j];
        const float be = head ? bez[j] : bexy[j];
        const float sc = g * rsqrtf(var + 1e-3f);
        const float sh = be - mu * sc;
        ws[(head ? OFF_SHZ : OFF_SHX) + j] = sh;
        unsigned short* dst = (unsigned short*)(ws + (head ? OFF_W1ZS : OFF_W1XS));
#pragma unroll
        for (int k = 0; k < 64; k++) dst[j * 64 + k] = f2bfh(w[k] * sc);
    } else if (t < 160) {
        const int j = t - 128;  // 0..31
        unsigned short* dst = (unsigned short*)(ws + OFF_WSEGS);
        for (int k = 0; k < 64; k++)
            dst[j * 64 + k] = (j < 20) ? f2bfh(wseg[k * 20 + j]) : (unsigned short)0;
    }
}

// ---------------- Pass 2: swapped-operand MFMA heads + lane-local tail + finalize ----------------
// R10 change: the 88 per-lane constant floats move to LDS (broadcast f32x4 reads per
// tile, short live ranges) -> resident regs ~140 < 170 cap -> LB(256,3) without spill.
__global__ __launch_bounds__(256, 3) void k_loss(
    const float* __restrict__ feat, const float* __restrict__ coord,
    const int* __restrict__ seg, const int* __restrict__ inst,
    const float* __restrict__ cent,
    const unsigned short* __restrict__ w1xs, const unsigned short* __restrict__ w1zs,
    const unsigned short* __restrict__ wsegs,
    const float* __restrict__ shxv, const float* __restrict__ shzv,
    const float* __restrict__ w2xy, const float* __restrict__ b2xy,
    const float* __restrict__ w2z,  const float* __restrict__ b2z,
    const float* __restrict__ bseg,
    int N, int ntiles, int tpb, float* __restrict__ acc, float* __restrict__ out) {
    __shared__ __align__(16) float ftile[2][4096];
    __shared__ __align__(16) float cl_shx[64], cl_shz[64], cl_w20[64], cl_w21[64], cl_w2z[64];
    __shared__ __align__(16) float cl_bs[32];
    __shared__ float red[4][8];

    const int t = threadIdx.x;
    const int lane = t & 63, l15 = lane & 15, grp = lane >> 4, wv = t >> 6;

    // loop-invariant weight A-frags in VGPRs (80 regs)
    bf16x8 ax[4][2], az[4][2], ag[2][2];
#pragma unroll
    for (int nt = 0; nt < 4; nt++)
#pragma unroll
        for (int h = 0; h < 2; h++) {
            ax[nt][h] = *(const bf16x8*)&w1xs[(nt * 16 + l15) * 64 + grp * 8 + h * 32];
            az[nt][h] = *(const bf16x8*)&w1zs[(nt * 16 + l15) * 64 + grp * 8 + h * 32];
        }
#pragma unroll
    for (int nt = 0; nt < 2; nt++)
#pragma unroll
        for (int h = 0; h < 2; h++)
            ag[nt][h] = *(const bf16x8*)&wsegs[(nt * 16 + l15) * 64 + grp * 8 + h * 32];

    // per-channel constants staged to LDS (read back per-tile as broadcast f32x4)
    if (t < 64) {
        cl_shx[t] = shxv[t];
        cl_shz[t] = shzv[t];
        cl_w20[t] = w2xy[2 * t];
        cl_w21[t] = w2xy[2 * t + 1];
        cl_w2z[t] = w2z[t];
    } else if (t < 96) {
        const int c = t - 64;
        cl_bs[c] = (c < 20) ? bseg[c] : -1e30f;
    }
    const float pb0 = b2xy[0], pb1 = b2xy[1], pbz = b2z[0];

    float s_nll = 0.f, s_vf = 0.f, s_l1xy = 0.f, s_cosxy = 0.f;
    float s_l1z = 0.f, s_cosz = 0.f, s_mask = 0.f;

    const int ti0 = blockIdx.x * tpb;
    const int tiend = min(ti0 + tpb, ntiles);

    auto stage = [&](int bufi, int ti) {
        const int row0 = ti * 64;
        if (row0 + 64 <= N) {
#pragma unroll
            for (int c = 0; c < 4; c++) {
                const int r = (wv * 4 + c) * 4 + grp;
                const int u = l15 ^ (r & 15);
                gload_lds16(&feat[(size_t)(row0 + r) * 64 + u * 4],
                            &ftile[bufi][(wv * 4 + c) * 256]);
            }
        } else {
#pragma unroll
            for (int u2 = 0; u2 < 4; u2++) {
                const int i = t + u2 * 256;
                const int r = i >> 4, u = (i & 15) ^ (r & 15);
                float4 v = make_float4(0.f, 0.f, 0.f, 0.f);
                if (row0 + r < N) v = *(const float4*)&feat[(size_t)(row0 + r) * 64 + u * 4];
                *(float4*)&ftile[bufi][i * 4] = v;
            }
        }
    };

    // point-scalar prefetch one tile ahead
    int p_tg = -1, p_iv = -1;
    float p_c0 = 0.f, p_c1 = 0.f, p_c2 = 0.f, p_e0 = 0.f, p_e1 = 0.f, p_e2 = 0.f;
    auto ptload = [&](int ti) {
        const int gp = ti * 64 + wv * 16 + l15;
        const bool inb = (gp < N);
        p_tg = inb ? seg[gp] : -1;
        p_iv = inb ? inst[gp] : -1;
        if (inb) {
            p_c0 = coord[(size_t)gp * 3]; p_c1 = coord[(size_t)gp * 3 + 1]; p_c2 = coord[(size_t)gp * 3 + 2];
            p_e0 = cent[(size_t)gp * 3];  p_e1 = cent[(size_t)gp * 3 + 1];  p_e2 = cent[(size_t)gp * 3 + 2];
        } else {
            p_c0 = p_c1 = p_c2 = p_e0 = p_e1 = p_e2 = 0.f;
        }
    };

    if (ti0 < tiend) { stage(0, ti0); ptload(ti0); }
    int cur = 0;
    for (int ti = ti0; ti < tiend; ++ti) {
        const int tg = p_tg, iv = p_iv;
        const float c0 = p_c0, c1 = p_c1, c2 = p_c2, e0 = p_e0, e1 = p_e1, e2 = p_e2;

        __syncthreads();
        if (ti + 1 < tiend) { stage(cur ^ 1, ti + 1); ptload(ti + 1); }

        const int p = wv * 16 + l15;
        const float* fb = ftile[cur];
        const float4 q0 = *(const float4*)&fb[(p * 16 + ((grp * 2)     ^ l15)) * 4];
        const float4 q1 = *(const float4*)&fb[(p * 16 + ((grp * 2 + 1) ^ l15)) * 4];
        const float4 q2 = *(const float4*)&fb[(p * 16 + ((8 + grp * 2) ^ l15)) * 4];
        const float4 q3 = *(const float4*)&fb[(p * 16 + ((9 + grp * 2) ^ l15)) * 4];
        BF8 b0, b1;
        b0.u[0] = f2bfh(q0.x); b0.u[1] = f2bfh(q0.y); b0.u[2] = f2bfh(q0.z); b0.u[3] = f2bfh(q0.w);
        b0.u[4] = f2bfh(q1.x); b0.u[5] = f2bfh(q1.y); b0.u[6] = f2bfh(q1.z); b0.u[7] = f2bfh(q1.w);
        b1.u[0] = f2bfh(q2.x); b1.u[1] = f2bfh(q2.y); b1.u[2] = f2bfh(q2.z); b1.u[3] = f2bfh(q2.w);
        b1.u[4] = f2bfh(q3.x); b1.u[5] = f2bfh(q3.y); b1.u[6] = f2bfh(q3.z); b1.u[7] = f2bfh(q3.w);

        // ---- seg head + CE (bs via LDS broadcast) ----
        f32x4 cg0 = *(const f32x4*)&cl_bs[grp * 4];
        cg0 = __builtin_amdgcn_mfma_f32_16x16x32_bf16(ag[0][0], b0.v, cg0, 0, 0, 0);
        cg0 = __builtin_amdgcn_mfma_f32_16x16x32_bf16(ag[0][1], b1.v, cg0, 0, 0, 0);
        f32x4 cg1 = *(const f32x4*)&cl_bs[16 + grp * 4];
        cg1 = __builtin_amdgcn_mfma_f32_16x16x32_bf16(ag[1][0], b0.v, cg1, 0, 0, 0);
        cg1 = __builtin_amdgcn_mfma_f32_16x16x32_bf16(ag[1][1], b1.v, cg1, 0, 0, 0);
        float lmax = cg0[0];
#pragma unroll
        for (int r = 1; r < 4; r++) lmax = fmaxf(lmax, cg0[r]);
#pragma unroll
        for (int r = 0; r < 4; r++) lmax = fmaxf(lmax, cg1[r]);
        lmax = fmaxf(lmax, __shfl_xor(lmax, 16));
        lmax = fmaxf(lmax, __shfl_xor(lmax, 32));
        float se = 0.f;
#pragma unroll
        for (int r = 0; r < 4; r++) se += __expf(cg0[r] - lmax);
#pragma unroll
        for (int r = 0; r < 4; r++) se += __expf(cg1[r] - lmax);
        se += __shfl_xor(se, 16); se += __shfl_xor(se, 32);
        const float lse = lmax + __logf(se);
        float lt = 0.f;
#pragma unroll
        for (int r = 0; r < 4; r++) lt += (grp * 4 + r == tg) ? cg0[r] : 0.f;
#pragma unroll
        for (int r = 0; r < 4; r++) lt += (16 + grp * 4 + r == tg) ? cg1[r] : 0.f;
        lt += __shfl_xor(lt, 16); lt += __shfl_xor(lt, 32);
        const float vf = (tg >= 0) ? 1.f : 0.f;
        s_nll += (lse - lt) * vf;
        s_vf += vf;

        // ---- xy + z heads (scale folded into weights; shift + w2 via LDS broadcast) ----
        float s0 = 0.f, s1 = 0.f, szv = 0.f;
#pragma unroll
        for (int nt = 0; nt < 4; nt++) {
            const int cb4 = nt * 16 + grp * 4;
            f32x4 cc = *(const f32x4*)&cl_shx[cb4];
            cc = __builtin_amdgcn_mfma_f32_16x16x32_bf16(ax[nt][0], b0.v, cc, 0, 0, 0);
            cc = __builtin_amdgcn_mfma_f32_16x16x32_bf16(ax[nt][1], b1.v, cc, 0, 0, 0);
            const f32x4 W0 = *(const f32x4*)&cl_w20[cb4];
            const f32x4 W1 = *(const f32x4*)&cl_w21[cb4];
#pragma unroll
            for (int r = 0; r < 4; r++) {
                const float hx = fmaxf(cc[r], 0.f);
                s0 = fmaf(hx, W0[r], s0);
                s1 = fmaf(hx, W1[r], s1);
            }
            f32x4 cz = *(const f32x4*)&cl_shz[cb4];
            cz = __builtin_amdgcn_mfma_f32_16x16x32_bf16(az[nt][0], b0.v, cz, 0, 0, 0);
            cz = __builtin_amdgcn_mfma_f32_16x16x32_bf16(az[nt][1], b1.v, cz, 0, 0, 0);
            const f32x4 WZ = *(const f32x4*)&cl_w2z[cb4];
#pragma unroll
            for (int r = 0; r < 4; r++) {
                const float hz = fmaxf(cz[r], 0.f);
                szv = fmaf(hz, WZ[r], szv);
            }
        }
        s0 += __shfl_xor(s0, 16);  s0 += __shfl_xor(s0, 32);
        s1 += __shfl_xor(s1, 16);  s1 += __shfl_xor(s1, 32);
        szv += __shfl_xor(szv, 16); szv += __shfl_xor(szv, 32);
        const float p0 = s0 + pb0, p1 = s1 + pb1, pz = szv + pbz;

        const float mk = (iv >= 0) ? 1.f : 0.f;
        const float a0 = e0 - c0, a1 = e1 - c1, a2 = e2 - c2;
        s_l1xy += (fabsf(a0 - p0) + fabsf(a1 - p1)) * mk;
        const float na = sqrtf(a0 * a0 + a1 * a1) + 1e-8f;
        const float nb = sqrtf(p0 * p0 + p1 * p1) + 1e-8f;
        s_cosxy -= ((a0 * p0 + a1 * p1) / (na * nb)) * mk;
        s_l1z += fabsf(a2 - pz) * mk;
        const float naz = fabsf(a2) + 1e-8f, nbz = fabsf(pz) + 1e-8f;
        s_cosz -= ((a2 * pz) / (naz * nbz)) * mk;
        s_mask += mk;

        cur ^= 1;
    }

    // block reduction; values replicated x4 across grp -> scale 0.25
    float v[7] = {s_nll * 0.25f, s_vf * 0.25f, s_l1xy * 0.25f, s_cosxy * 0.25f,
                  s_l1z * 0.25f, s_cosz * 0.25f, s_mask * 0.25f};
#pragma unroll
    for (int i = 0; i < 7; i++) {
#pragma unroll
        for (int o = 32; o > 0; o >>= 1) v[i] += __shfl_down(v[i], o);
    }
    if (lane == 0) {
#pragma unroll
        for (int i = 0; i < 7; i++) red[wv][i] = v[i];
    }
    __syncthreads();
    if (t < 7) {
        float s = red[0][t] + red[1][t] + red[2][t] + red[3][t];
        atomicAdd(&acc[t], s);
    }
    __syncthreads();   // drains the acc atomics before the done handshake
    if (t == 0) {
        __threadfence();
        int* done = (int*)(acc + (OFF_DONE - OFF_ACC));
        if (atomicAdd(done, 1) == (int)gridDim.x - 1) {
            __threadfence();
            float sv[7];
#pragma unroll
            for (int i = 0; i < 7; i++) sv[i] = atomicAdd(&acc[i], 0.f);
            const float segl = sv[0] / sv[1];
            const float den = sv[6] + 1e-8f;
            const float l1xy = sv[2] / den, cosxy = sv[3] / den;
            const float l1z = sv[4] / den, cosz = sv[5] / den;
            out[0] = segl + l1xy + l1xy + 0.5f * (l1z + cosz);
            out[1] = segl;
            out[2] = l1xy;
            out[3] = cosxy;
            out[4] = l1z;
            out[5] = cosz;
        }
    }
}

extern "C" void kernel_launch(void* const* d_in, const int* in_sizes, int n_in,
                              void* d_out, int out_size, void* d_ws, size_t ws_size,
                              hipStream_t stream) {
    const float* feat  = (const float*)d_in[0];
    const float* coord = (const float*)d_in[1];
    const int*   segm  = (const int*)d_in[2];
    const int*   inst  = (const int*)d_in[3];
    const float* cent  = (const float*)d_in[4];
    const float* w1xy  = (const float*)d_in[5];
    const float* b1xy  = (const float*)d_in[6];
    const float* gxy   = (const float*)d_in[7];
    const float* bexy  = (const float*)d_in[8];
    const float* w2xy  = (const float*)d_in[9];
    const float* b2xy  = (const float*)d_in[10];
    const float* w1z   = (const float*)d_in[11];
    const float* b1z   = (const float*)d_in[12];
    const float* gz    = (const float*)d_in[13];
    const float* bez   = (const float*)d_in[14];
    const float* w2z   = (const float*)d_in[15];
    const float* b2z   = (const float*)d_in[16];
    const float* wseg  = (const float*)d_in[17];
    const float* bseg  = (const float*)d_in[18];

    const int N = in_sizes[0] / 64;
    float* ws = (float*)d_ws;
    const int ntiles = (N + 63) >> 6;

    const int grid_s = 512;
    const int tpb_s = (ntiles + grid_s - 1) / grid_s;
    const int grid_l = 768;
    const int tpb_l = (ntiles + grid_l - 1) / grid_l;

    hipMemsetAsync(d_ws, 0, OFF_ZEND * sizeof(float), stream);

    k_stats<<<grid_s, 256, 0, stream>>>(feat, N, ntiles, tpb_s, ws);
    k_prep<<<1, 256, 0, stream>>>(w1xy, b1xy, gxy, bexy, w1z, b1z, gz, bez, wseg,
                                  (float)N, ws);
    k_loss<<<grid_l, 256, 0, stream>>>(
        feat, coord, segm, inst, cent,
        (const unsigned short*)(ws + OFF_W1XS),
        (const unsigned short*)(ws + OFF_W1ZS),
        (const unsigned short*)(ws + OFF_WSEGS),
        ws + OFF_SHX, ws + OFF_SHZ,
        w2xy, b2xy, w2z, b2z, bseg, N, ntiles, tpb_l,
        ws + OFF_ACC, (float*)d_out);
}

// Round 11
// 188.899 us; speedup vs baseline: 4.0073x; 1.2004x over previous
//
#include <hip/hip_runtime.h>
#include <hip/hip_bf16.h>

// Workspace layout (float indices). [COLSUM..DONE] zeroed by one memset each call.
#define OFF_COLSUM 0        // 64
#define OFF_S      64       // 4096
#define OFF_ACC    4160     // 8 loss accumulators (7 used)
#define OFF_DONE   4168     // 1 (int done-counter)
#define OFF_ZEND   4169     // memset extent (floats)
#define OFF_SHX    4176     // 64 BN shift xy
#define OFF_SHZ    4240     // 64 BN shift z
#define OFF_W1XS   4304     // ushort[4096] (w1_xy^T * sc, bf16, [ch j][k])
#define OFF_W1ZS   6352     // ushort[4096]
#define OFF_WSEGS  8400     // ushort[2048] (w_seg^T bf16, rows 20..31 = 0)

typedef __attribute__((ext_vector_type(8))) short bf16x8;
typedef __attribute__((ext_vector_type(4))) float f32x4;

__device__ __forceinline__ unsigned short f2bfh(float x) {
    __hip_bfloat16 h = __float2bfloat16(x);
    return *reinterpret_cast<unsigned short*>(&h);
}

union BF8 { bf16x8 v; unsigned short u[8]; };

__device__ __forceinline__ void gload_lds16(const void* g, void* l) {
    __builtin_amdgcn_global_load_lds((const __attribute__((address_space(1))) void*)g,
                                     (__attribute__((address_space(3))) void*)l, 16, 0, 0);
}

// Shared staging layout (point-major, swizzled; R4-proven):
//   16B unit i of ftile holds feat[r = i>>4][4*((i&15) ^ (r&15)) .. +3]

// ---------------- Pass 1: colsum + S = F^T F via MFMA, column-frags ----------------
// EXACT R4 body/config (grid 512, 2 blocks/CU) — measured ~85-90 us, 0 conflicts.
// Structural note: 64 ds_read_b32/lane/tile is forced by the point-major layout
// (global_load_lds needs linear dest); all alternatives measured worse (R3/R5/R7).
__global__ __launch_bounds__(256, 2) void k_stats(const float* __restrict__ feat,
                                                  int N, int ntiles, int tpb,
                                                  float* __restrict__ ws) {
    __shared__ __align__(16) float ftile[2][4096];
    const int t = threadIdx.x;
    const int lane = t & 63, l15 = lane & 15, grp = lane >> 4, wv = t >> 6;

    const f32x4 z4 = {0.f, 0.f, 0.f, 0.f};
    f32x4 acc[4] = {z4, z4, z4, z4};
    float csum = 0.f;

    const int l3 = l15 & 3;
    const int cb_base = l15 >> 2;   // c>>2 = g*4 + cb_base
    const int g1x8 = (grp & 1) * 8; // p&15 = g1x8 | kk

    const int ti0 = blockIdx.x * tpb;
    const int tiend = min(ti0 + tpb, ntiles);

    auto stage = [&](int bufi, int ti) {
        const int row0 = ti * 64;
        if (row0 + 64 <= N) {
#pragma unroll
            for (int c = 0; c < 4; c++) {
                const int r = (wv * 4 + c) * 4 + grp;
                const int u = l15 ^ (r & 15);
                gload_lds16(&feat[(size_t)(row0 + r) * 64 + u * 4],
                            &ftile[bufi][(wv * 4 + c) * 256]);
            }
        } else {
#pragma unroll
            for (int u2 = 0; u2 < 4; u2++) {
                const int i = t + u2 * 256;
                const int r = i >> 4, u = (i & 15) ^ (r & 15);
                float4 v = make_float4(0.f, 0.f, 0.f, 0.f);
                if (row0 + r < N) v = *(const float4*)&feat[(size_t)(row0 + r) * 64 + u * 4];
                *(float4*)&ftile[bufi][i * 4] = v;
            }
        }
    };

    if (ti0 < tiend) stage(0, ti0);
    int cur = 0;
    for (int ti = ti0; ti < tiend; ++ti) {
        __syncthreads();                      // drains staging vmcnt; prev reads done
        if (ti + 1 < tiend) stage(cur ^ 1, ti + 1);
        const float* fb = ftile[cur];

        // column frags: fr[s][h] lane(grp,l15) = F[h*32+grp*8+kk][g*16+l15], g=(wv+s)&3
        bf16x8 fr[4][2];
#pragma unroll
        for (int s = 0; s < 4; s++) {
            const int g = (wv + s) & 3;
            const int cb = (g * 4 + cb_base) ^ g1x8;
#pragma unroll
            for (int h = 0; h < 2; h++) {
                const int pbase = h * 32 + grp * 8;
                float vs[8];
#pragma unroll
                for (int kk = 0; kk < 8; kk++)
                    vs[kk] = fb[(pbase + kk) * 64 + ((cb ^ kk) << 2) + l3];
                BF8 fv;
#pragma unroll
                for (int kk = 0; kk < 8; kk++) fv.u[kk] = f2bfh(vs[kk]);
                fr[s][h] = fv.v;
                if (s == 0) {
#pragma unroll
                    for (int kk = 0; kk < 8; kk++) csum += vs[kk];
                }
            }
        }
        // D = F^T(g=wv rows) * F(g=(wv+s) cols); frag doubles as A and B
#pragma unroll
        for (int s = 0; s < 4; s++) {
            acc[s] = __builtin_amdgcn_mfma_f32_16x16x32_bf16(fr[0][0], fr[s][0], acc[s], 0, 0, 0);
            acc[s] = __builtin_amdgcn_mfma_f32_16x16x32_bf16(fr[0][1], fr[s][1], acc[s], 0, 0, 0);
        }
        cur ^= 1;
    }

    // S[row = wv*16 + grp*4 + r][col = ((wv+s)&3)*16 + l15]
    float* S = ws + OFF_S;
#pragma unroll
    for (int s = 0; s < 4; s++) {
        const int gj = (wv + s) & 3;
#pragma unroll
        for (int r = 0; r < 4; r++)
            atomicAdd(&S[(wv * 16 + grp * 4 + r) * 64 + gj * 16 + l15], acc[s][r]);
    }
    // colsum of channel wv*16 + l15: lane holds its grp's 16 points; reduce over grp
    csum += __shfl_xor(csum, 16);
    csum += __shfl_xor(csum, 32);
    if (grp == 0) atomicAdd(&ws[OFF_COLSUM + wv * 16 + l15], csum);
}

// ------------- Prep: BN scale/shift; scaled bf16 weights (R4-proven) -------------
__global__ __launch_bounds__(256) void k_prep(
    const float* __restrict__ w1xy, const float* __restrict__ b1xy,
    const float* __restrict__ gxy,  const float* __restrict__ bexy,
    const float* __restrict__ w1z,  const float* __restrict__ b1z,
    const float* __restrict__ gz,   const float* __restrict__ bez,
    const float* __restrict__ wseg, float Nf, float* __restrict__ ws) {
    __shared__ float S[64][64];
    __shared__ float cs[64];
    const int t = threadIdx.x;

    for (int i = t; i < 4096; i += 256) ((float*)S)[i] = ws[OFF_S + i];
    if (t < 64) cs[t] = ws[OFF_COLSUM + t];
    __syncthreads();

    if (t < 128) {
        const int head = t >> 6, j = t & 63;
        const float* w1 = head ? w1z : w1xy;
        float w[64];
#pragma unroll
        for (int k = 0; k < 64; k++) w[k] = w1[k * 64 + j];
        float d = 0.f;
#pragma unroll
        for (int k = 0; k < 64; k++) d = fmaf(cs[k], w[k], d);
        float quad = 0.f;
#pragma unroll
        for (int k = 0; k < 64; k++) {
            float rd = 0.f;
#pragma unroll
            for (int l = 0; l < 64; l++) rd = fmaf(S[k][l], w[l], rd);
            quad = fmaf(w[k], rd, quad);
        }
        const float b1 = head ? b1z[j] : b1xy[j];
        const float mu  = d / Nf + b1;
        const float eh2 = quad / Nf + 2.f * b1 * d / Nf + b1 * b1;
        const float var = eh2 - mu * mu;
        const float g  = head ? gz[j]  : gxy[j];
        const float be = head ? bez[j] : bexy[j];
        const float sc = g * rsqrtf(var + 1e-3f);
        const float sh = be - mu * sc;
        ws[(head ? OFF_SHZ : OFF_SHX) + j] = sh;
        unsigned short* dst = (unsigned short*)(ws + (head ? OFF_W1ZS : OFF_W1XS));
#pragma unroll
        for (int k = 0; k < 64; k++) dst[j * 64 + k] = f2bfh(w[k] * sc);
    } else if (t < 160) {
        const int j = t - 128;  // 0..31
        unsigned short* dst = (unsigned short*)(ws + OFF_WSEGS);
        for (int k = 0; k < 64; k++)
            dst[j * 64 + k] = (j < 20) ? f2bfh(wseg[k * 20 + j]) : (unsigned short)0;
    }
}

// ---------------- Pass 2: swapped-operand MFMA heads + lane-local tail + finalize ----------------
// EXACT R4 body/config (LB(256,2), grid 512, in-register constants — measured ~75 us).
// Structural note: resident state ~168 unified regs; every 3+-block variant spilled
// (R8: 850 MB, R9: 600 MB, R10 consts-in-LDS: still slower). 2 blocks/CU is the cap.
__global__ __launch_bounds__(256, 2) void k_loss(
    const float* __restrict__ feat, const float* __restrict__ coord,
    const int* __restrict__ seg, const int* __restrict__ inst,
    const float* __restrict__ cent,
    const unsigned short* __restrict__ w1xs, const unsigned short* __restrict__ w1zs,
    const unsigned short* __restrict__ wsegs,
    const float* __restrict__ shxv, const float* __restrict__ shzv,
    const float* __restrict__ w2xy, const float* __restrict__ b2xy,
    const float* __restrict__ w2z,  const float* __restrict__ b2z,
    const float* __restrict__ bseg,
    int N, int ntiles, int tpb, float* __restrict__ acc, float* __restrict__ out) {
    __shared__ __align__(16) float ftile[2][4096];
    __shared__ float red[4][8];

    const int t = threadIdx.x;
    const int lane = t & 63, l15 = lane & 15, grp = lane >> 4, wv = t >> 6;

    // loop-invariant weight A-frags in VGPRs
    bf16x8 ax[4][2], az[4][2], ag[2][2];
#pragma unroll
    for (int nt = 0; nt < 4; nt++)
#pragma unroll
        for (int h = 0; h < 2; h++) {
            ax[nt][h] = *(const bf16x8*)&w1xs[(nt * 16 + l15) * 64 + grp * 8 + h * 32];
            az[nt][h] = *(const bf16x8*)&w1zs[(nt * 16 + l15) * 64 + grp * 8 + h * 32];
        }
#pragma unroll
    for (int nt = 0; nt < 2; nt++)
#pragma unroll
        for (int h = 0; h < 2; h++)
            ag[nt][h] = *(const bf16x8*)&wsegs[(nt * 16 + l15) * 64 + grp * 8 + h * 32];

    // per-lane constants: channel c = nt*16 + grp*4 + r
    float shx_c[4][4], shz_c[4][4], w20[4][4], w21[4][4], w2zc[4][4], bs_c[2][4];
#pragma unroll
    for (int nt = 0; nt < 4; nt++)
#pragma unroll
        for (int r = 0; r < 4; r++) {
            const int c = nt * 16 + grp * 4 + r;
            shx_c[nt][r] = shxv[c]; shz_c[nt][r] = shzv[c];
            w20[nt][r] = w2xy[c * 2]; w21[nt][r] = w2xy[c * 2 + 1];
            w2zc[nt][r] = w2z[c];
        }
#pragma unroll
    for (int nt = 0; nt < 2; nt++)
#pragma unroll
        for (int r = 0; r < 4; r++) {
            const int c = nt * 16 + grp * 4 + r;
            bs_c[nt][r] = (c < 20) ? bseg[c] : -1e30f;
        }
    const float pb0 = b2xy[0], pb1 = b2xy[1], pbz = b2z[0];

    float s_nll = 0.f, s_vf = 0.f, s_l1xy = 0.f, s_cosxy = 0.f;
    float s_l1z = 0.f, s_cosz = 0.f, s_mask = 0.f;

    const int ti0 = blockIdx.x * tpb;
    const int tiend = min(ti0 + tpb, ntiles);

    auto stage = [&](int bufi, int ti) {
        const int row0 = ti * 64;
        if (row0 + 64 <= N) {
#pragma unroll
            for (int c = 0; c < 4; c++) {
                const int r = (wv * 4 + c) * 4 + grp;
                const int u = l15 ^ (r & 15);
                gload_lds16(&feat[(size_t)(row0 + r) * 64 + u * 4],
                            &ftile[bufi][(wv * 4 + c) * 256]);
            }
        } else {
#pragma unroll
            for (int u2 = 0; u2 < 4; u2++) {
                const int i = t + u2 * 256;
                const int r = i >> 4, u = (i & 15) ^ (r & 15);
                float4 v = make_float4(0.f, 0.f, 0.f, 0.f);
                if (row0 + r < N) v = *(const float4*)&feat[(size_t)(row0 + r) * 64 + u * 4];
                *(float4*)&ftile[bufi][i * 4] = v;
            }
        }
    };

    // point-scalar prefetch one tile ahead
    int p_tg = -1, p_iv = -1;
    float p_c0 = 0.f, p_c1 = 0.f, p_c2 = 0.f, p_e0 = 0.f, p_e1 = 0.f, p_e2 = 0.f;
    auto ptload = [&](int ti) {
        const int gp = ti * 64 + wv * 16 + l15;
        const bool inb = (gp < N);
        p_tg = inb ? seg[gp] : -1;
        p_iv = inb ? inst[gp] : -1;
        if (inb) {
            p_c0 = coord[(size_t)gp * 3]; p_c1 = coord[(size_t)gp * 3 + 1]; p_c2 = coord[(size_t)gp * 3 + 2];
            p_e0 = cent[(size_t)gp * 3];  p_e1 = cent[(size_t)gp * 3 + 1];  p_e2 = cent[(size_t)gp * 3 + 2];
        } else {
            p_c0 = p_c1 = p_c2 = p_e0 = p_e1 = p_e2 = 0.f;
        }
    };

    if (ti0 < tiend) { stage(0, ti0); ptload(ti0); }
    int cur = 0;
    for (int ti = ti0; ti < tiend; ++ti) {
        const int tg = p_tg, iv = p_iv;
        const float c0 = p_c0, c1 = p_c1, c2 = p_c2, e0 = p_e0, e1 = p_e1, e2 = p_e2;

        __syncthreads();
        if (ti + 1 < tiend) { stage(cur ^ 1, ti + 1); ptload(ti + 1); }

        const int p = wv * 16 + l15;
        const float* fb = ftile[cur];
        const float4 q0 = *(const float4*)&fb[(p * 16 + ((grp * 2)     ^ l15)) * 4];
        const float4 q1 = *(const float4*)&fb[(p * 16 + ((grp * 2 + 1) ^ l15)) * 4];
        const float4 q2 = *(const float4*)&fb[(p * 16 + ((8 + grp * 2) ^ l15)) * 4];
        const float4 q3 = *(const float4*)&fb[(p * 16 + ((9 + grp * 2) ^ l15)) * 4];
        BF8 b0, b1;
        b0.u[0] = f2bfh(q0.x); b0.u[1] = f2bfh(q0.y); b0.u[2] = f2bfh(q0.z); b0.u[3] = f2bfh(q0.w);
        b0.u[4] = f2bfh(q1.x); b0.u[5] = f2bfh(q1.y); b0.u[6] = f2bfh(q1.z); b0.u[7] = f2bfh(q1.w);
        b1.u[0] = f2bfh(q2.x); b1.u[1] = f2bfh(q2.y); b1.u[2] = f2bfh(q2.z); b1.u[3] = f2bfh(q2.w);
        b1.u[4] = f2bfh(q3.x); b1.u[5] = f2bfh(q3.y); b1.u[6] = f2bfh(q3.z); b1.u[7] = f2bfh(q3.w);

        // ---- seg head + CE ----
        f32x4 cg0 = {bs_c[0][0], bs_c[0][1], bs_c[0][2], bs_c[0][3]};
        cg0 = __builtin_amdgcn_mfma_f32_16x16x32_bf16(ag[0][0], b0.v, cg0, 0, 0, 0);
        cg0 = __builtin_amdgcn_mfma_f32_16x16x32_bf16(ag[0][1], b1.v, cg0, 0, 0, 0);
        f32x4 cg1 = {bs_c[1][0], bs_c[1][1], bs_c[1][2], bs_c[1][3]};
        cg1 = __builtin_amdgcn_mfma_f32_16x16x32_bf16(ag[1][0], b0.v, cg1, 0, 0, 0);
        cg1 = __builtin_amdgcn_mfma_f32_16x16x32_bf16(ag[1][1], b1.v, cg1, 0, 0, 0);
        float lmax = cg0[0];
#pragma unroll
        for (int r = 1; r < 4; r++) lmax = fmaxf(lmax, cg0[r]);
#pragma unroll
        for (int r = 0; r < 4; r++) lmax = fmaxf(lmax, cg1[r]);
        lmax = fmaxf(lmax, __shfl_xor(lmax, 16));
        lmax = fmaxf(lmax, __shfl_xor(lmax, 32));
        float se = 0.f;
#pragma unroll
        for (int r = 0; r < 4; r++) se += __expf(cg0[r] - lmax);
#pragma unroll
        for (int r = 0; r < 4; r++) se += __expf(cg1[r] - lmax);
        se += __shfl_xor(se, 16); se += __shfl_xor(se, 32);
        const float lse = lmax + __logf(se);
        float lt = 0.f;
#pragma unroll
        for (int r = 0; r < 4; r++) lt += (grp * 4 + r == tg) ? cg0[r] : 0.f;
#pragma unroll
        for (int r = 0; r < 4; r++) lt += (16 + grp * 4 + r == tg) ? cg1[r] : 0.f;
        lt += __shfl_xor(lt, 16); lt += __shfl_xor(lt, 32);
        const float vf = (tg >= 0) ? 1.f : 0.f;
        s_nll += (lse - lt) * vf;
        s_vf += vf;

        // ---- xy + z heads (scale folded into weights, shift via C-init) ----
        float s0 = 0.f, s1 = 0.f, szv = 0.f;
#pragma unroll
        for (int nt = 0; nt < 4; nt++) {
            f32x4 cc = {shx_c[nt][0], shx_c[nt][1], shx_c[nt][2], shx_c[nt][3]};
            cc = __builtin_amdgcn_mfma_f32_16x16x32_bf16(ax[nt][0], b0.v, cc, 0, 0, 0);
            cc = __builtin_amdgcn_mfma_f32_16x16x32_bf16(ax[nt][1], b1.v, cc, 0, 0, 0);
#pragma unroll
            for (int r = 0; r < 4; r++) {
                const float hx = fmaxf(cc[r], 0.f);
                s0 = fmaf(hx, w20[nt][r], s0);
                s1 = fmaf(hx, w21[nt][r], s1);
            }
            f32x4 cz = {shz_c[nt][0], shz_c[nt][1], shz_c[nt][2], shz_c[nt][3]};
            cz = __builtin_amdgcn_mfma_f32_16x16x32_bf16(az[nt][0], b0.v, cz, 0, 0, 0);
            cz = __builtin_amdgcn_mfma_f32_16x16x32_bf16(az[nt][1], b1.v, cz, 0, 0, 0);
#pragma unroll
            for (int r = 0; r < 4; r++) {
                const float hz = fmaxf(cz[r], 0.f);
                szv = fmaf(hz, w2zc[nt][r], szv);
            }
        }
        s0 += __shfl_xor(s0, 16);  s0 += __shfl_xor(s0, 32);
        s1 += __shfl_xor(s1, 16);  s1 += __shfl_xor(s1, 32);
        szv += __shfl_xor(szv, 16); szv += __shfl_xor(szv, 32);
        const float p0 = s0 + pb0, p1 = s1 + pb1, pz = szv + pbz;

        const float mk = (iv >= 0) ? 1.f : 0.f;
        const float a0 = e0 - c0, a1 = e1 - c1, a2 = e2 - c2;
        s_l1xy += (fabsf(a0 - p0) + fabsf(a1 - p1)) * mk;
        const float na = sqrtf(a0 * a0 + a1 * a1) + 1e-8f;
        const float nb = sqrtf(p0 * p0 + p1 * p1) + 1e-8f;
        s_cosxy -= ((a0 * p0 + a1 * p1) / (na * nb)) * mk;
        s_l1z += fabsf(a2 - pz) * mk;
        const float naz = fabsf(a2) + 1e-8f, nbz = fabsf(pz) + 1e-8f;
        s_cosz -= ((a2 * pz) / (naz * nbz)) * mk;
        s_mask += mk;

        cur ^= 1;
    }

    // block reduction; values replicated x4 across grp -> scale 0.25
    float v[7] = {s_nll * 0.25f, s_vf * 0.25f, s_l1xy * 0.25f, s_cosxy * 0.25f,
                  s_l1z * 0.25f, s_cosz * 0.25f, s_mask * 0.25f};
#pragma unroll
    for (int i = 0; i < 7; i++) {
#pragma unroll
        for (int o = 32; o > 0; o >>= 1) v[i] += __shfl_down(v[i], o);
    }
    if (lane == 0) {
#pragma unroll
        for (int i = 0; i < 7; i++) red[wv][i] = v[i];
    }
    __syncthreads();
    if (t < 7) {
        float s = red[0][t] + red[1][t] + red[2][t] + red[3][t];
        atomicAdd(&acc[t], s);
    }
    __syncthreads();   // drains the acc atomics before the done handshake
    if (t == 0) {
        __threadfence();
        int* done = (int*)(acc + (OFF_DONE - OFF_ACC));
        if (atomicAdd(done, 1) == (int)gridDim.x - 1) {
            __threadfence();
            float sv[7];
#pragma unroll
            for (int i = 0; i < 7; i++) sv[i] = atomicAdd(&acc[i], 0.f);
            const float segl = sv[0] / sv[1];
            const float den = sv[6] + 1e-8f;
            const float l1xy = sv[2] / den, cosxy = sv[3] / den;
            const float l1z = sv[4] / den, cosz = sv[5] / den;
            out[0] = segl + l1xy + l1xy + 0.5f * (l1z + cosz);
            out[1] = segl;
            out[2] = l1xy;
            out[3] = cosxy;
            out[4] = l1z;
            out[5] = cosz;
        }
    }
}

extern "C" void kernel_launch(void* const* d_in, const int* in_sizes, int n_in,
                              void* d_out, int out_size, void* d_ws, size_t ws_size,
                              hipStream_t stream) {
    const float* feat  = (const float*)d_in[0];
    const float* coord = (const float*)d_in[1];
    const int*   segm  = (const int*)d_in[2];
    const int*   inst  = (const int*)d_in[3];
    const float* cent  = (const float*)d_in[4];
    const float* w1xy  = (const float*)d_in[5];
    const float* b1xy  = (const float*)d_in[6];
    const float* gxy   = (const float*)d_in[7];
    const float* bexy  = (const float*)d_in[8];
    const float* w2xy  = (const float*)d_in[9];
    const float* b2xy  = (const float*)d_in[10];
    const float* w1z   = (const float*)d_in[11];
    const float* b1z   = (const float*)d_in[12];
    const float* gz    = (const float*)d_in[13];
    const float* bez   = (const float*)d_in[14];
    const float* w2z   = (const float*)d_in[15];
    const float* b2z   = (const float*)d_in[16];
    const float* wseg  = (const float*)d_in[17];
    const float* bseg  = (const float*)d_in[18];

    const int N = in_sizes[0] / 64;
    float* ws = (float*)d_ws;
    const int ntiles = (N + 63) >> 6;

    const int grid_s = 512;
    const int tpb_s = (ntiles + grid_s - 1) / grid_s;
    const int grid_l = 512;
    const int tpb_l = (ntiles + grid_l - 1) / grid_l;

    hipMemsetAsync(d_ws, 0, OFF_ZEND * sizeof(float), stream);

    k_stats<<<grid_s, 256, 0, stream>>>(feat, N, ntiles, tpb_s, ws);
    k_prep<<<1, 256, 0, stream>>>(w1xy, b1xy, gxy, bexy, w1z, b1z, gz, bez, wseg,
                                  (float)N, ws);
    k_loss<<<grid_l, 256, 0, stream>>>(
        feat, coord, segm, inst, cent,
        (const unsigned short*)(ws + OFF_W1XS),
        (const unsigned short*)(ws + OFF_W1ZS),
        (const unsigned short*)(ws + OFF_WSEGS),
        ws + OFF_SHX, ws + OFF_SHZ,
        w2xy, b2xy, w2z, b2z, bseg, N, ntiles, tpb_l,
        ws + OFF_ACC, (float*)d_out);
}